// Round 1
// baseline (706.094 us; speedup 1.0000x reference)
//
#include <hip/hip_runtime.h>
#include <stdint.h>

// Problem constants
#define B_     2
#define N_     2048
#define QD_    1024
#define H_     16
#define DH_    64
#define INNER_ 1024
#define SCALE_ 0.125f

typedef unsigned short u16;
typedef __attribute__((ext_vector_type(8))) short bf16x8;   // 8 bf16 = 4 VGPRs (MFMA A/B frag)
typedef __attribute__((ext_vector_type(4))) float f32x4;    // MFMA C/D frag
typedef __attribute__((ext_vector_type(4))) unsigned short u16x4;

// ---- bf16 helpers (RNE) ----
__device__ inline u16 f2bf(float f) {
    union { float f; uint32_t u; } c; c.f = f;
    uint32_t r = c.u + 0x7FFFu + ((c.u >> 16) & 1u);
    return (u16)(r >> 16);
}
__device__ inline float bf2f(u16 s) {
    union { uint32_t u; float f; } c; c.u = ((uint32_t)s) << 16;
    return c.f;
}
__device__ inline void split2(float v, u16 &h, u16 &l) {
    u16 hs = f2bf(v);
    h = hs;
    l = f2bf(v - bf2f(hs));
}

// ---- precompute: split x into hi/lo bf16 ----
__global__ __launch_bounds__(256) void split_x_kernel(
    const float* __restrict__ x, u16* __restrict__ xh, u16* __restrict__ xl, int n4)
{
    int idx = blockIdx.x * 256 + threadIdx.x;
    if (idx >= n4) return;
    float4 v = ((const float4*)x)[idx];
    u16x4 hv, lv;
    u16 h, l;
    split2(v.x, h, l); hv.x = h; lv.x = l;
    split2(v.y, h, l); hv.y = h; lv.y = l;
    split2(v.z, h, l); hv.z = h; lv.z = l;
    split2(v.w, h, l); hv.w = h; lv.w = l;
    ((u16x4*)xh)[idx] = hv;
    ((u16x4*)xl)[idx] = lv;
}

// ---- precompute: transpose [R][C] fp32 -> [C][R] hi/lo bf16 ----
__global__ __launch_bounds__(256) void transpose_split(
    const float* __restrict__ src, int R, int C,
    u16* __restrict__ dhi, u16* __restrict__ dlo)
{
    __shared__ float t[32][33];
    int bx = blockIdx.x * 32;  // col offset in src
    int by = blockIdx.y * 32;  // row offset in src
    int x = threadIdx.x;
    for (int yy = threadIdx.y; yy < 32; yy += 8)
        t[yy][x] = src[(size_t)(by + yy) * C + bx + x];
    __syncthreads();
    for (int i = threadIdx.y; i < 32; i += 8) {
        float v = t[x][i];                       // src[by+x][bx+i]
        u16 h, l; split2(v, h, l);
        size_t o = (size_t)(bx + i) * R + by + x; // dst[bx+i][by+x]
        dhi[o] = h; dlo[o] = l;
    }
}

// ---- compensated bf16 GEMM core: C[M][N] = A[M][1024] * B^T (B stored [N][1024]) ----
// 128x128 block, BK=32, 4 waves (2x2), each wave 4x4 subtiles of 16x16x32 MFMA.
// LDS rows padded to 40 bf16 (80B): frag-read conflicts reduce to free 2-way.

#define GLD 40

// stage 1: x @ [Wq|Wkv], scatter to per-head q(hi/lo), k(hi/lo), v
__global__ __launch_bounds__(256) void gemm_qkv(
    const u16* __restrict__ Ah, const u16* __restrict__ Al,
    const u16* __restrict__ Bh, const u16* __restrict__ Bl,
    u16* __restrict__ qh, u16* __restrict__ ql,
    u16* __restrict__ kh, u16* __restrict__ kl,
    u16* __restrict__ vb)
{
    __shared__ __align__(16) u16 sAh[128 * GLD], sAl[128 * GLD], sBh[128 * GLD], sBl[128 * GLD];
    const int tid = threadIdx.x;
    const int wave = tid >> 6, lane = tid & 63;
    const int quad = lane >> 4, l16 = lane & 15;
    const int wm = wave >> 1, wn = wave & 1;
    const int bm = blockIdx.y * 128, bn = blockIdx.x * 128;

    f32x4 acc[4][4];
#pragma unroll
    for (int i = 0; i < 4; i++)
#pragma unroll
        for (int j = 0; j < 4; j++) acc[i][j] = (f32x4){0.f, 0.f, 0.f, 0.f};

    const int row_s = tid >> 2, cg = tid & 3;
    for (int k0 = 0; k0 < 1024; k0 += 32) {
        __syncthreads();
#pragma unroll
        for (int it = 0; it < 2; it++) {
            int row = row_s + it * 64;
            int off = row * GLD + cg * 8;
            size_t ga = (size_t)(bm + row) * 1024 + k0 + cg * 8;
            size_t gb = (size_t)(bn + row) * 1024 + k0 + cg * 8;
            *(bf16x8*)&sAh[off] = *(const bf16x8*)&Ah[ga];
            *(bf16x8*)&sAl[off] = *(const bf16x8*)&Al[ga];
            *(bf16x8*)&sBh[off] = *(const bf16x8*)&Bh[gb];
            *(bf16x8*)&sBl[off] = *(const bf16x8*)&Bl[gb];
        }
        __syncthreads();
        bf16x8 fah[4], fal[4], fbh[4], fbl[4];
#pragma unroll
        for (int s = 0; s < 4; s++) {
            int ra = (wm * 64 + s * 16 + l16) * GLD + quad * 8;
            int rb = (wn * 64 + s * 16 + l16) * GLD + quad * 8;
            fah[s] = *(const bf16x8*)&sAh[ra];
            fal[s] = *(const bf16x8*)&sAl[ra];
            fbh[s] = *(const bf16x8*)&sBh[rb];
            fbl[s] = *(const bf16x8*)&sBl[rb];
        }
#pragma unroll
        for (int sm = 0; sm < 4; sm++)
#pragma unroll
            for (int sn = 0; sn < 4; sn++) {
                acc[sm][sn] = __builtin_amdgcn_mfma_f32_16x16x32_bf16(fah[sm], fbh[sn], acc[sm][sn], 0, 0, 0);
                acc[sm][sn] = __builtin_amdgcn_mfma_f32_16x16x32_bf16(fah[sm], fbl[sn], acc[sm][sn], 0, 0, 0);
                acc[sm][sn] = __builtin_amdgcn_mfma_f32_16x16x32_bf16(fal[sm], fbh[sn], acc[sm][sn], 0, 0, 0);
            }
    }
    // epilogue: scatter into per-head [bh][n][64] layouts
#pragma unroll
    for (int sm = 0; sm < 4; sm++) {
        int rowb = bm + wm * 64 + sm * 16 + quad * 4;
#pragma unroll
        for (int sn = 0; sn < 4; sn++) {
            int col = bn + wn * 64 + sn * 16 + l16;
            int region = col >> 10;        // 0:q 1:k 2:v
            int hh = (col >> 6) & 15;      // head
            int d = col & 63;
#pragma unroll
            for (int r = 0; r < 4; r++) {
                int row = rowb + r;
                int b = row >> 11, i = row & 2047;
                size_t o = (((size_t)(b * H_ + hh)) * N_ + i) * DH_ + d;
                float val = acc[sm][sn][r];
                if (region == 0) { u16 a, c; split2(val, a, c); qh[o] = a; ql[o] = c; }
                else if (region == 1) { u16 a, c; split2(val, a, c); kh[o] = a; kl[o] = c; }
                else { vb[o] = f2bf(val); }
            }
        }
    }
}

// stage 3: O @ Wo + bo -> fp32 out
__global__ __launch_bounds__(256) void gemm_out(
    const u16* __restrict__ Ah, const u16* __restrict__ Al,
    const u16* __restrict__ Bh, const u16* __restrict__ Bl,
    const float* __restrict__ bo, float* __restrict__ out)
{
    __shared__ __align__(16) u16 sAh[128 * GLD], sAl[128 * GLD], sBh[128 * GLD], sBl[128 * GLD];
    const int tid = threadIdx.x;
    const int wave = tid >> 6, lane = tid & 63;
    const int quad = lane >> 4, l16 = lane & 15;
    const int wm = wave >> 1, wn = wave & 1;
    const int bm = blockIdx.y * 128, bn = blockIdx.x * 128;

    f32x4 acc[4][4];
#pragma unroll
    for (int i = 0; i < 4; i++)
#pragma unroll
        for (int j = 0; j < 4; j++) acc[i][j] = (f32x4){0.f, 0.f, 0.f, 0.f};

    const int row_s = tid >> 2, cg = tid & 3;
    for (int k0 = 0; k0 < 1024; k0 += 32) {
        __syncthreads();
#pragma unroll
        for (int it = 0; it < 2; it++) {
            int row = row_s + it * 64;
            int off = row * GLD + cg * 8;
            size_t ga = (size_t)(bm + row) * 1024 + k0 + cg * 8;
            size_t gb = (size_t)(bn + row) * 1024 + k0 + cg * 8;
            *(bf16x8*)&sAh[off] = *(const bf16x8*)&Ah[ga];
            *(bf16x8*)&sAl[off] = *(const bf16x8*)&Al[ga];
            *(bf16x8*)&sBh[off] = *(const bf16x8*)&Bh[gb];
            *(bf16x8*)&sBl[off] = *(const bf16x8*)&Bl[gb];
        }
        __syncthreads();
        bf16x8 fah[4], fal[4], fbh[4], fbl[4];
#pragma unroll
        for (int s = 0; s < 4; s++) {
            int ra = (wm * 64 + s * 16 + l16) * GLD + quad * 8;
            int rb = (wn * 64 + s * 16 + l16) * GLD + quad * 8;
            fah[s] = *(const bf16x8*)&sAh[ra];
            fal[s] = *(const bf16x8*)&sAl[ra];
            fbh[s] = *(const bf16x8*)&sBh[rb];
            fbl[s] = *(const bf16x8*)&sBl[rb];
        }
#pragma unroll
        for (int sm = 0; sm < 4; sm++)
#pragma unroll
            for (int sn = 0; sn < 4; sn++) {
                acc[sm][sn] = __builtin_amdgcn_mfma_f32_16x16x32_bf16(fah[sm], fbh[sn], acc[sm][sn], 0, 0, 0);
                acc[sm][sn] = __builtin_amdgcn_mfma_f32_16x16x32_bf16(fah[sm], fbl[sn], acc[sm][sn], 0, 0, 0);
                acc[sm][sn] = __builtin_amdgcn_mfma_f32_16x16x32_bf16(fal[sm], fbh[sn], acc[sm][sn], 0, 0, 0);
            }
    }
#pragma unroll
    for (int sm = 0; sm < 4; sm++) {
        int rowb = bm + wm * 64 + sm * 16 + quad * 4;
#pragma unroll
        for (int sn = 0; sn < 4; sn++) {
            int col = bn + wn * 64 + sn * 16 + l16;
            float bv = bo[col];
#pragma unroll
            for (int r = 0; r < 4; r++)
                out[(size_t)(rowb + r) * 1024 + col] = acc[sm][sn][r] + bv;
        }
    }
}

// ---- stage 2: flash attention with bias + key mask ----
// grid (N/64, B*H). 4 waves; each wave owns 16 query rows. K-tile = 64 keys.
#define LDT 72   // 64 + 8 pad: 144B row stride -> free 2-way LDS conflicts

__global__ __launch_bounds__(256) void attn_kernel(
    const u16* __restrict__ qh, const u16* __restrict__ ql,
    const u16* __restrict__ kh, const u16* __restrict__ kl,
    const u16* __restrict__ vb,
    const float* __restrict__ bias, const int* __restrict__ mask,
    u16* __restrict__ oh, u16* __restrict__ ol)
{
    __shared__ __align__(16) u16 sKh[64 * LDT], sKl[64 * LDT], sVt[64 * LDT];
    __shared__ __align__(16) u16 sP[4][16 * LDT];

    const int bh = blockIdx.y, b = bh >> 4, h = bh & 15;
    const int qbase = blockIdx.x * 64;
    const int tid = threadIdx.x, wave = tid >> 6, lane = tid & 63;
    const int quad = lane >> 4, l16 = lane & 15;

    // Q fragments (A-layout: row = lane&15, k = quad*8+j), held all kernel
    bf16x8 aqh[2], aql[2];
    {
        size_t qoff = ((size_t)bh * N_ + qbase + wave * 16 + l16) * DH_ + quad * 8;
        aqh[0] = *(const bf16x8*)&qh[qoff];
        aqh[1] = *(const bf16x8*)&qh[qoff + 32];
        aql[0] = *(const bf16x8*)&ql[qoff];
        aql[1] = *(const bf16x8*)&ql[qoff + 32];
    }
    f32x4 oacc[4];
#pragma unroll
    for (int nd = 0; nd < 4; nd++) oacc[nd] = (f32x4){0.f, 0.f, 0.f, 0.f};
    float m_s[4] = {-INFINITY, -INFINITY, -INFINITY, -INFINITY};
    float l_s[4] = {0.f, 0.f, 0.f, 0.f};

    for (int j0 = 0; j0 < N_; j0 += 64) {
        __syncthreads();   // previous-iter LDS reads done before overwrite
        // stage K hi/lo [key][d] and V transposed [d][key]
#pragma unroll
        for (int it = 0; it < 2; it++) {
            int c = tid + it * 256;
            int jr = c >> 3, dg = c & 7;
            size_t g = ((size_t)bh * N_ + j0 + jr) * DH_ + dg * 8;
            *(bf16x8*)&sKh[jr * LDT + dg * 8] = *(const bf16x8*)&kh[g];
            *(bf16x8*)&sKl[jr * LDT + dg * 8] = *(const bf16x8*)&kl[g];
            bf16x8 v8 = *(const bf16x8*)&vb[g];
#pragma unroll
            for (int jj = 0; jj < 8; jj++) sVt[(dg * 8 + jj) * LDT + jr] = (u16)v8[jj];
        }
        __syncthreads();

        // S = (qh+ql)(kh+kl)^T  (compensated, 3 MFMAs per k-step)
        f32x4 S[4];
#pragma unroll
        for (int n = 0; n < 4; n++) {
            f32x4 a = (f32x4){0.f, 0.f, 0.f, 0.f};
#pragma unroll
            for (int s = 0; s < 2; s++) {
                bf16x8 kfh = *(const bf16x8*)&sKh[(n * 16 + l16) * LDT + s * 32 + quad * 8];
                bf16x8 kfl = *(const bf16x8*)&sKl[(n * 16 + l16) * LDT + s * 32 + quad * 8];
                a = __builtin_amdgcn_mfma_f32_16x16x32_bf16(aqh[s], kfh, a, 0, 0, 0);
                a = __builtin_amdgcn_mfma_f32_16x16x32_bf16(aqh[s], kfl, a, 0, 0, 0);
                a = __builtin_amdgcn_mfma_f32_16x16x32_bf16(aql[s], kfh, a, 0, 0, 0);
            }
            S[n] = a;
        }
        // scale + bias + key mask (C-layout: row = quad*4+r, col = n*16+l16)
        const int qr0 = qbase + wave * 16 + quad * 4;
#pragma unroll
        for (int n = 0; n < 4; n++) {
            int key = j0 + n * 16 + l16;
            int mok = mask[b * N_ + key];
            const float* bp = bias + ((size_t)b * N_ + qr0) * N_ + key;
#pragma unroll
            for (int r = 0; r < 4; r++) {
                float sv = S[n][r] * SCALE_ + bp[(size_t)r * N_];
                S[n][r] = mok ? sv : -1e30f;
            }
        }
        // online softmax per local row (quad*4+r), 16-lane reductions
#pragma unroll
        for (int r = 0; r < 4; r++) {
            float mt = fmaxf(fmaxf(S[0][r], S[1][r]), fmaxf(S[2][r], S[3][r]));
#pragma unroll
            for (int off = 1; off < 16; off <<= 1) mt = fmaxf(mt, __shfl_xor(mt, off));
            float mn = fmaxf(m_s[r], mt);
            float alpha = __expf(m_s[r] - mn);
            m_s[r] = mn;
            float rs = 0.f;
#pragma unroll
            for (int n = 0; n < 4; n++) {
                float p = __expf(S[n][r] - mn);
                S[n][r] = p; rs += p;
            }
#pragma unroll
            for (int off = 1; off < 16; off <<= 1) rs += __shfl_xor(rs, off);
            l_s[r] = l_s[r] * alpha + rs;
#pragma unroll
            for (int nd = 0; nd < 4; nd++) oacc[nd][r] *= alpha;
        }
        // P: C-layout -> LDS -> A-layout (m120 round-trip)
#pragma unroll
        for (int n = 0; n < 4; n++)
#pragma unroll
            for (int r = 0; r < 4; r++)
                sP[wave][(quad * 4 + r) * LDT + n * 16 + l16] = f2bf(S[n][r]);
        __syncthreads();
        // O += P @ V
#pragma unroll
        for (int s = 0; s < 2; s++) {
            bf16x8 pf = *(const bf16x8*)&sP[wave][l16 * LDT + s * 32 + quad * 8];
#pragma unroll
            for (int nd = 0; nd < 4; nd++) {
                bf16x8 vf = *(const bf16x8*)&sVt[(nd * 16 + l16) * LDT + s * 32 + quad * 8];
                oacc[nd] = __builtin_amdgcn_mfma_f32_16x16x32_bf16(pf, vf, oacc[nd], 0, 0, 0);
            }
        }
    }
    // normalize and write O as hi/lo bf16 in [b][n][h*64+d]
#pragma unroll
    for (int nd = 0; nd < 4; nd++)
#pragma unroll
        for (int r = 0; r < 4; r++) {
            float val = oacc[nd][r] / l_s[r];
            int row = qbase + wave * 16 + quad * 4 + r;
            int col = h * 64 + nd * 16 + l16;
            u16 a, c; split2(val, a, c);
            size_t o = ((size_t)b * N_ + row) * INNER_ + col;
            oh[o] = a; ol[o] = c;
        }
}

extern "C" void kernel_launch(void* const* d_in, const int* in_sizes, int n_in,
                              void* d_out, int out_size, void* d_ws, size_t ws_size,
                              hipStream_t stream)
{
    const float* x    = (const float*)d_in[0];
    const float* bias = (const float*)d_in[1];
    const int*   mask = (const int*)d_in[2];
    const float* Wq   = (const float*)d_in[3];
    const float* Wkv  = (const float*)d_in[4];
    const float* Wo   = (const float*)d_in[5];
    const float* bo   = (const float*)d_in[6];
    float* out = (float*)d_out;

    char* w = (char*)d_ws;
    const size_t MB = 1024 * 1024;
    u16* xs_h  = (u16*)(w);             // 8 MB  [4096][1024]
    u16* xs_l  = (u16*)(w + 8 * MB);    // 8 MB
    u16* wT_h  = (u16*)(w + 16 * MB);   // 6 MB  [3072][1024]  (WqT rows 0..1023, WkvT rows 1024..3071)
    u16* wT_l  = (u16*)(w + 22 * MB);   // 6 MB
    u16* woT_h = (u16*)(w + 28 * MB);   // 2 MB  [1024][1024]
    u16* woT_l = (u16*)(w + 30 * MB);   // 2 MB
    u16* q_h   = (u16*)(w + 32 * MB);   // 8 MB  [32][2048][64]
    u16* q_l   = (u16*)(w + 40 * MB);
    u16* k_h   = (u16*)(w + 48 * MB);
    u16* k_l   = (u16*)(w + 56 * MB);
    u16* v_b   = (u16*)(w + 64 * MB);   // 8 MB
    u16* o_h   = xs_h;                  // alias: x splits dead after gemm_qkv
    u16* o_l   = xs_l;
    // total ws use: 72 MB

    dim3 tb(32, 8);
    split_x_kernel<<<4096, 256, 0, stream>>>(x, xs_h, xs_l, (B_ * N_ * QD_) / 4);
    transpose_split<<<dim3(32, 32), tb, 0, stream>>>(Wq, 1024, 1024, wT_h, wT_l);
    transpose_split<<<dim3(64, 32), tb, 0, stream>>>(Wkv, 1024, 2048, wT_h + 1024 * 1024, wT_l + 1024 * 1024);
    transpose_split<<<dim3(32, 32), tb, 0, stream>>>(Wo, 1024, 1024, woT_h, woT_l);

    gemm_qkv<<<dim3(24, 32), 256, 0, stream>>>(xs_h, xs_l, wT_h, wT_l, q_h, q_l, k_h, k_l, v_b);
    attn_kernel<<<dim3(32, 32), 256, 0, stream>>>(q_h, q_l, k_h, k_l, v_b, bias, mask, o_h, o_l);
    gemm_out<<<dim3(8, 32), 256, 0, stream>>>(o_h, o_l, woT_h, woT_l, bo, out);
}

// Round 2
// 351.549 us; speedup vs baseline: 2.0085x; 2.0085x over previous
//
#include <hip/hip_runtime.h>
#include <stdint.h>

#define B_     2
#define N_     2048
#define QD_    1024
#define H_     16
#define DH_    64
#define INNER_ 1024
#define SCALE_ 0.125f

typedef unsigned short u16;
typedef __attribute__((ext_vector_type(8))) short bf16x8;   // 8 bf16 = 4 VGPRs
typedef __attribute__((ext_vector_type(4))) float f32x4;    // MFMA C/D frag
typedef __attribute__((ext_vector_type(4))) unsigned short u16x4;

// ---- bf16 helpers (RNE) ----
__device__ inline u16 f2bf(float f) {
    union { float f; uint32_t u; } c; c.f = f;
    uint32_t r = c.u + 0x7FFFu + ((c.u >> 16) & 1u);
    return (u16)(r >> 16);
}
__device__ inline float bf2f(u16 s) {
    union { uint32_t u; float f; } c; c.u = ((uint32_t)s) << 16;
    return c.f;
}
__device__ inline void split2(float v, u16 &h, u16 &l) {
    u16 hs = f2bf(v);
    h = hs;
    l = f2bf(v - bf2f(hs));
}

// async global->LDS, 16B per lane; LDS dest = wave-uniform base + lane*16
__device__ inline void gll16(const void* g, void* l) {
    __builtin_amdgcn_global_load_lds(
        (const __attribute__((address_space(1))) unsigned int*)g,
        (__attribute__((address_space(3))) unsigned int*)l, 16, 0, 0);
}

// ---- precompute: split x into hi/lo bf16 ----
__global__ __launch_bounds__(256) void split_x_kernel(
    const float* __restrict__ x, u16* __restrict__ xh, u16* __restrict__ xl, int n4)
{
    int idx = blockIdx.x * 256 + threadIdx.x;
    if (idx >= n4) return;
    float4 v = ((const float4*)x)[idx];
    u16x4 hv, lv;
    u16 h, l;
    split2(v.x, h, l); hv.x = h; lv.x = l;
    split2(v.y, h, l); hv.y = h; lv.y = l;
    split2(v.z, h, l); hv.z = h; lv.z = l;
    split2(v.w, h, l); hv.w = h; lv.w = l;
    ((u16x4*)xh)[idx] = hv;
    ((u16x4*)xl)[idx] = lv;
}

// ---- precompute: transpose [R][C] fp32 -> [C][R] hi/lo bf16 ----
__global__ __launch_bounds__(256) void transpose_split(
    const float* __restrict__ src, int R, int C,
    u16* __restrict__ dhi, u16* __restrict__ dlo)
{
    __shared__ float t[32][33];
    int bx = blockIdx.x * 32;
    int by = blockIdx.y * 32;
    int x = threadIdx.x;
    for (int yy = threadIdx.y; yy < 32; yy += 8)
        t[yy][x] = src[(size_t)(by + yy) * C + bx + x];
    __syncthreads();
    for (int i = threadIdx.y; i < 32; i += 8) {
        float v = t[x][i];
        u16 h, l; split2(v, h, l);
        size_t o = (size_t)(bx + i) * R + by + x;
        dhi[o] = h; dlo[o] = l;
    }
}

// ---- precompute: bias2[b][q][k] = mask[b][k] ? bf16(bias) : -1e30 ----
__global__ __launch_bounds__(256) void bias2_kernel(
    const float* __restrict__ bias, const int* __restrict__ mask, u16* __restrict__ bias2)
{
    int idx = blockIdx.x * 256 + threadIdx.x;      // one thread per 8 elements
    int k8 = idx & 255;
    int q  = (idx >> 8) & 2047;
    int b  = idx >> 19;
    size_t base = ((size_t)b * N_ + q) * N_ + k8 * 8;
    const float4* bp = (const float4*)&bias[base];
    float4 b0 = bp[0], b1 = bp[1];
    const int4* mp = (const int4*)&mask[b * N_ + k8 * 8];
    int4 m0 = mp[0], m1 = mp[1];
    const u16 NEG = f2bf(-1e30f);
    bf16x8 o;
    o[0] = m0.x ? f2bf(b0.x) : NEG;
    o[1] = m0.y ? f2bf(b0.y) : NEG;
    o[2] = m0.z ? f2bf(b0.z) : NEG;
    o[3] = m0.w ? f2bf(b0.w) : NEG;
    o[4] = m1.x ? f2bf(b1.x) : NEG;
    o[5] = m1.y ? f2bf(b1.y) : NEG;
    o[6] = m1.z ? f2bf(b1.z) : NEG;
    o[7] = m1.w ? f2bf(b1.w) : NEG;
    *(bf16x8*)&bias2[base] = o;
}

// ---- stage 1: compensated GEMM x @ [Wq|Wkv], global_load_lds + XOR swizzle ----
// LDS tile: [128 rows][32 u16], no pad; slot(row,g) holds global group g^(row&3).
__global__ __launch_bounds__(256) void gemm_qkv(
    const u16* __restrict__ Ah, const u16* __restrict__ Al,
    const u16* __restrict__ Bh, const u16* __restrict__ Bl,
    u16* __restrict__ qh, u16* __restrict__ ql,
    u16* __restrict__ kb, u16* __restrict__ vT)
{
    __shared__ __align__(16) u16 sAh[128 * 32], sAl[128 * 32], sBh[128 * 32], sBl[128 * 32];
    const int tid = threadIdx.x;
    const int wave = tid >> 6, lane = tid & 63;
    const int quad = lane >> 4, l16 = lane & 15;
    const int wm = wave >> 1, wn = wave & 1;
    const int bm = blockIdx.y * 128, bn = blockIdx.x * 128;

    f32x4 acc[4][4];
#pragma unroll
    for (int i = 0; i < 4; i++)
#pragma unroll
        for (int j = 0; j < 4; j++) acc[i][j] = (f32x4){0.f, 0.f, 0.f, 0.f};

    const int row0 = tid >> 2, g = tid & 3;
    for (int k0 = 0; k0 < 1024; k0 += 32) {
        __syncthreads();
#pragma unroll
        for (int it = 0; it < 2; it++) {
            int row = row0 + it * 64;
            int gc = (g ^ (row & 3)) * 8;
            size_t ga = (size_t)(bm + row) * 1024 + k0 + gc;
            size_t gb = (size_t)(bn + row) * 1024 + k0 + gc;
            int lo = it * 2048 + wave * 512;
            gll16(&Ah[ga], &sAh[lo]);
            gll16(&Al[ga], &sAl[lo]);
            gll16(&Bh[gb], &sBh[lo]);
            gll16(&Bl[gb], &sBl[lo]);
        }
        __syncthreads();
        bf16x8 fah[4], fal[4], fbh[4], fbl[4];
#pragma unroll
        for (int s = 0; s < 4; s++) {
            int ra = wm * 64 + s * 16 + l16;
            int rb = wn * 64 + s * 16 + l16;
            int ca = (quad ^ (ra & 3)) * 8;
            int cb = (quad ^ (rb & 3)) * 8;
            fah[s] = *(const bf16x8*)&sAh[ra * 32 + ca];
            fal[s] = *(const bf16x8*)&sAl[ra * 32 + ca];
            fbh[s] = *(const bf16x8*)&sBh[rb * 32 + cb];
            fbl[s] = *(const bf16x8*)&sBl[rb * 32 + cb];
        }
#pragma unroll
        for (int sm = 0; sm < 4; sm++)
#pragma unroll
            for (int sn = 0; sn < 4; sn++) {
                acc[sm][sn] = __builtin_amdgcn_mfma_f32_16x16x32_bf16(fah[sm], fbh[sn], acc[sm][sn], 0, 0, 0);
                acc[sm][sn] = __builtin_amdgcn_mfma_f32_16x16x32_bf16(fah[sm], fbl[sn], acc[sm][sn], 0, 0, 0);
                acc[sm][sn] = __builtin_amdgcn_mfma_f32_16x16x32_bf16(fal[sm], fbh[sn], acc[sm][sn], 0, 0, 0);
            }
    }
    // epilogue: q pre-scaled by SCALE, split hi/lo; k -> bf16; v -> V^T [bh][d][n]
#pragma unroll
    for (int sm = 0; sm < 4; sm++) {
        int rowb = bm + wm * 64 + sm * 16 + quad * 4;
        int bb = rowb >> 11, i0 = rowb & 2047;
#pragma unroll
        for (int sn = 0; sn < 4; sn++) {
            int col = bn + wn * 64 + sn * 16 + l16;
            int region = col >> 10;
            int hh = (col >> 6) & 15;
            int d = col & 63;
            if (region == 0) {
#pragma unroll
                for (int r = 0; r < 4; r++) {
                    float val = acc[sm][sn][r] * SCALE_;
                    u16 a, c; split2(val, a, c);
                    size_t o = (((size_t)(bb * H_ + hh)) * N_ + i0 + r) * DH_ + d;
                    qh[o] = a; ql[o] = c;
                }
            } else if (region == 1) {
#pragma unroll
                for (int r = 0; r < 4; r++) {
                    size_t o = (((size_t)(bb * H_ + hh)) * N_ + i0 + r) * DH_ + d;
                    kb[o] = f2bf(acc[sm][sn][r]);
                }
            } else {
                u16x4 pv;
#pragma unroll
                for (int r = 0; r < 4; r++) pv[r] = f2bf(acc[sm][sn][r]);
                *(u16x4*)&vT[(((size_t)(bb * H_ + hh)) * DH_ + d) * N_ + i0] = pv;
            }
        }
    }
}

// ---- stage 3: O(bf16) @ Wo(hi/lo) + bo -> fp32 ----
__global__ __launch_bounds__(256) void gemm_out(
    const u16* __restrict__ Ab,
    const u16* __restrict__ Bh, const u16* __restrict__ Bl,
    const float* __restrict__ bo, float* __restrict__ out)
{
    __shared__ __align__(16) u16 sA[128 * 32], sBh[128 * 32], sBl[128 * 32];
    const int tid = threadIdx.x;
    const int wave = tid >> 6, lane = tid & 63;
    const int quad = lane >> 4, l16 = lane & 15;
    const int wm = wave >> 1, wn = wave & 1;
    const int bm = blockIdx.y * 128, bn = blockIdx.x * 128;

    f32x4 acc[4][4];
#pragma unroll
    for (int i = 0; i < 4; i++)
#pragma unroll
        for (int j = 0; j < 4; j++) acc[i][j] = (f32x4){0.f, 0.f, 0.f, 0.f};

    const int row0 = tid >> 2, g = tid & 3;
    for (int k0 = 0; k0 < 1024; k0 += 32) {
        __syncthreads();
#pragma unroll
        for (int it = 0; it < 2; it++) {
            int row = row0 + it * 64;
            int gc = (g ^ (row & 3)) * 8;
            size_t ga = (size_t)(bm + row) * 1024 + k0 + gc;
            size_t gb = (size_t)(bn + row) * 1024 + k0 + gc;
            int lo = it * 2048 + wave * 512;
            gll16(&Ab[ga], &sA[lo]);
            gll16(&Bh[gb], &sBh[lo]);
            gll16(&Bl[gb], &sBl[lo]);
        }
        __syncthreads();
        bf16x8 fa[4], fbh[4], fbl[4];
#pragma unroll
        for (int s = 0; s < 4; s++) {
            int ra = wm * 64 + s * 16 + l16;
            int rb = wn * 64 + s * 16 + l16;
            int ca = (quad ^ (ra & 3)) * 8;
            int cb = (quad ^ (rb & 3)) * 8;
            fa[s]  = *(const bf16x8*)&sA[ra * 32 + ca];
            fbh[s] = *(const bf16x8*)&sBh[rb * 32 + cb];
            fbl[s] = *(const bf16x8*)&sBl[rb * 32 + cb];
        }
#pragma unroll
        for (int sm = 0; sm < 4; sm++)
#pragma unroll
            for (int sn = 0; sn < 4; sn++) {
                acc[sm][sn] = __builtin_amdgcn_mfma_f32_16x16x32_bf16(fa[sm], fbh[sn], acc[sm][sn], 0, 0, 0);
                acc[sm][sn] = __builtin_amdgcn_mfma_f32_16x16x32_bf16(fa[sm], fbl[sn], acc[sm][sn], 0, 0, 0);
            }
    }
#pragma unroll
    for (int sm = 0; sm < 4; sm++) {
        int rowb = bm + wm * 64 + sm * 16 + quad * 4;
#pragma unroll
        for (int sn = 0; sn < 4; sn++) {
            int col = bn + wn * 64 + sn * 16 + l16;
            float bv = bo[col];
#pragma unroll
            for (int r = 0; r < 4; r++)
                out[(size_t)(rowb + r) * 1024 + col] = acc[sm][sn][r] + bv;
        }
    }
}

// ---- stage 2: flash attention, software-pipelined, no running max ----
#define LDK 72   // K/V^T LDS row stride (u16): frag reads uniform-banked
#define LDB 76   // bias tile stride: conflict-free scalar reads
#define LDP 68   // P tile stride: 4-row quad offset = 8 banks -> conflict-free

__global__ __launch_bounds__(256, 4) void attn_kernel(
    const u16* __restrict__ qh, const u16* __restrict__ ql,
    const u16* __restrict__ kb, const u16* __restrict__ vT,
    const u16* __restrict__ bias2, u16* __restrict__ ob)
{
    __shared__ __align__(16) u16 sK[64 * LDK], sV[64 * LDK], sB[64 * LDB], sP[4][16 * LDP];
    const int bh = blockIdx.y, b = bh >> 4, h = bh & 15;
    const int qbase = blockIdx.x * 64;
    const int tid = threadIdx.x, wave = tid >> 6, lane = tid & 63;
    const int quad = lane >> 4, l16 = lane & 15;

    // Q A-frags (pre-scaled by SCALE in gemm_qkv), resident all kernel
    bf16x8 aqh[2], aql[2];
    {
        size_t qo = ((size_t)bh * N_ + qbase + wave * 16 + l16) * DH_ + quad * 8;
        aqh[0] = *(const bf16x8*)&qh[qo]; aqh[1] = *(const bf16x8*)&qh[qo + 32];
        aql[0] = *(const bf16x8*)&ql[qo]; aql[1] = *(const bf16x8*)&ql[qo + 32];
    }
    f32x4 oacc[4];
#pragma unroll
    for (int nd = 0; nd < 4; nd++) oacc[nd] = (f32x4){0.f, 0.f, 0.f, 0.f};
    float l_s[4] = {0.f, 0.f, 0.f, 0.f};

    const int srow = tid >> 3, sg = tid & 7;     // staging: 32 rows x 8 groups per pass
    const size_t kbase = (size_t)bh * N_ * DH_;
    const size_t vbase = (size_t)bh * DH_ * N_;
    const size_t bbase = ((size_t)b * N_ + qbase) * N_;

    // prologue: prefetch tile 0 into registers
    bf16x8 pK[2], pV[2], pB[2];
#pragma unroll
    for (int it = 0; it < 2; it++) {
        int r = srow + it * 32;
        pK[it] = *(const bf16x8*)&kb[kbase + (size_t)r * DH_ + sg * 8];
        pV[it] = *(const bf16x8*)&vT[vbase + (size_t)r * N_ + sg * 8];
        pB[it] = *(const bf16x8*)&bias2[bbase + (size_t)r * N_ + sg * 8];
    }

    for (int jt = 0; jt < 32; jt++) {
        // commit staged tile to LDS
#pragma unroll
        for (int it = 0; it < 2; it++) {
            int r = srow + it * 32;
            *(bf16x8*)&sK[r * LDK + sg * 8] = pK[it];
            *(bf16x8*)&sV[r * LDK + sg * 8] = pV[it];
            *(bf16x8*)&sB[r * LDB + sg * 8] = pB[it];
        }
        __syncthreads();
        // prefetch next tile (latency hidden by this tile's compute)
        {
            int j0n = (jt + 1 < 32) ? (jt + 1) * 64 : 0;
#pragma unroll
            for (int it = 0; it < 2; it++) {
                int r = srow + it * 32;
                pK[it] = *(const bf16x8*)&kb[kbase + (size_t)(j0n + r) * DH_ + sg * 8];
                pV[it] = *(const bf16x8*)&vT[vbase + (size_t)r * N_ + j0n + sg * 8];
                pB[it] = *(const bf16x8*)&bias2[bbase + (size_t)r * N_ + j0n + sg * 8];
            }
        }
        // S = Q K^T (q hi/lo x k hi: 2 MFMAs per k-step)
        f32x4 S[4];
#pragma unroll
        for (int n = 0; n < 4; n++) {
            f32x4 a = (f32x4){0.f, 0.f, 0.f, 0.f};
#pragma unroll
            for (int s = 0; s < 2; s++) {
                bf16x8 kf = *(const bf16x8*)&sK[(n * 16 + l16) * LDK + s * 32 + quad * 8];
                a = __builtin_amdgcn_mfma_f32_16x16x32_bf16(aqh[s], kf, a, 0, 0, 0);
                a = __builtin_amdgcn_mfma_f32_16x16x32_bf16(aql[s], kf, a, 0, 0, 0);
            }
            S[n] = a;
        }
        // bias add + exp (no max subtraction: logits bounded, fp32 safe)
        const int brow = wave * 16 + quad * 4;
#pragma unroll
        for (int n = 0; n < 4; n++)
#pragma unroll
            for (int r = 0; r < 4; r++) {
                float bv = bf2f(sB[(brow + r) * LDB + n * 16 + l16]);
                S[n][r] = __expf(S[n][r] + bv);
            }
        // l accumulation (16-lane shuffle within quad rows)
#pragma unroll
        for (int r = 0; r < 4; r++) {
            float rs = (S[0][r] + S[1][r]) + (S[2][r] + S[3][r]);
            rs += __shfl_xor(rs, 1); rs += __shfl_xor(rs, 2);
            rs += __shfl_xor(rs, 4); rs += __shfl_xor(rs, 8);
            l_s[r] += rs;
        }
        // P: C-layout -> LDS -> A-layout (per-wave buffer; same-wave RAW, no barrier)
#pragma unroll
        for (int n = 0; n < 4; n++)
#pragma unroll
            for (int r = 0; r < 4; r++)
                sP[wave][(quad * 4 + r) * LDP + n * 16 + l16] = f2bf(S[n][r]);
        // O += P @ V
#pragma unroll
        for (int s = 0; s < 2; s++) {
            bf16x8 pf = *(const bf16x8*)&sP[wave][l16 * LDP + s * 32 + quad * 8];
#pragma unroll
            for (int nd = 0; nd < 4; nd++) {
                bf16x8 vf = *(const bf16x8*)&sV[(nd * 16 + l16) * LDK + s * 32 + quad * 8];
                oacc[nd] = __builtin_amdgcn_mfma_f32_16x16x32_bf16(pf, vf, oacc[nd], 0, 0, 0);
            }
        }
        __syncthreads();
    }
    // normalize and store O as bf16 [b][n][h*64+d]
#pragma unroll
    for (int nd = 0; nd < 4; nd++)
#pragma unroll
        for (int r = 0; r < 4; r++) {
            float val = oacc[nd][r] / l_s[r];
            int row = qbase + wave * 16 + quad * 4 + r;
            int col = h * 64 + nd * 16 + l16;
            ob[((size_t)b * N_ + row) * INNER_ + col] = f2bf(val);
        }
}

extern "C" void kernel_launch(void* const* d_in, const int* in_sizes, int n_in,
                              void* d_out, int out_size, void* d_ws, size_t ws_size,
                              hipStream_t stream)
{
    const float* x    = (const float*)d_in[0];
    const float* bias = (const float*)d_in[1];
    const int*   mask = (const int*)d_in[2];
    const float* Wq   = (const float*)d_in[3];
    const float* Wkv  = (const float*)d_in[4];
    const float* Wo   = (const float*)d_in[5];
    const float* bo   = (const float*)d_in[6];
    float* out = (float*)d_out;

    char* w = (char*)d_ws;
    const size_t MB = 1024 * 1024;
    u16* q_h   = (u16*)(w);             //  0..8   [32][2048][64]
    u16* q_l   = (u16*)(w + 8 * MB);    //  8..16
    u16* k_b   = (u16*)(w + 16 * MB);   // 16..24
    u16* v_T   = (u16*)(w + 24 * MB);   // 24..32  [32][64][2048]
    u16* xs_h  = (u16*)(w + 32 * MB);   // 32..40  (dead after gemm_qkv)
    u16* xs_l  = (u16*)(w + 40 * MB);   // 40..48  (dead after gemm_qkv)
    u16* bias2 = (u16*)(w + 32 * MB);   // 32..48.8 (written after gemm_qkv; tail overlaps dead wT_h)
    u16* wT_h  = (u16*)(w + 48 * MB);   // 48..54  [3072][1024] (dead after gemm_qkv)
    u16* wT_l  = (u16*)(w + 54 * MB);   // 54..60
    u16* woT_h = (u16*)(w + 60 * MB);   // 60..62
    u16* woT_l = (u16*)(w + 62 * MB);   // 62..64
    u16* o_b   = (u16*)(w + 64 * MB);   // 64..72  [2][2048][1024]
    // total: 72 MB

    dim3 tb(32, 8);
    split_x_kernel<<<4096, 256, 0, stream>>>(x, xs_h, xs_l, (B_ * N_ * QD_) / 4);
    transpose_split<<<dim3(32, 32), tb, 0, stream>>>(Wq, 1024, 1024, wT_h, wT_l);
    transpose_split<<<dim3(64, 32), tb, 0, stream>>>(Wkv, 1024, 2048, wT_h + 1024 * 1024, wT_l + 1024 * 1024);
    transpose_split<<<dim3(32, 32), tb, 0, stream>>>(Wo, 1024, 1024, woT_h, woT_l);

    gemm_qkv<<<dim3(24, 32), 256, 0, stream>>>(xs_h, xs_l, wT_h, wT_l, q_h, q_l, k_b, v_T);
    bias2_kernel<<<4096, 256, 0, stream>>>(bias, mask, bias2);
    attn_kernel<<<dim3(32, 32), 256, 0, stream>>>(q_h, q_l, k_b, v_T, bias2, o_b);
    gemm_out<<<dim3(8, 32), 256, 0, stream>>>(o_b, woT_h, woT_l, bo, out);
}

// Round 3
// 340.956 us; speedup vs baseline: 2.0709x; 1.0311x over previous
//
#include <hip/hip_runtime.h>
#include <stdint.h>

#define B_     2
#define N_     2048
#define QD_    1024
#define H_     16
#define DH_    64
#define INNER_ 1024
#define SCALE_ 0.125f

typedef unsigned short u16;
typedef __attribute__((ext_vector_type(8))) short bf16x8;   // 8 bf16 = 4 VGPRs
typedef __attribute__((ext_vector_type(4))) float f32x4;    // MFMA C/D frag
typedef __attribute__((ext_vector_type(4))) unsigned short u16x4;

// ---- bf16 helpers (RNE) ----
__device__ inline u16 f2bf(float f) {
    union { float f; uint32_t u; } c; c.f = f;
    uint32_t r = c.u + 0x7FFFu + ((c.u >> 16) & 1u);
    return (u16)(r >> 16);
}
__device__ inline float bf2f(u16 s) {
    union { uint32_t u; float f; } c; c.u = ((uint32_t)s) << 16;
    return c.f;
}
__device__ inline void split2(float v, u16 &h, u16 &l) {
    u16 hs = f2bf(v);
    h = hs;
    l = f2bf(v - bf2f(hs));
}

__device__ inline void gll16(const void* g, void* l) {
    __builtin_amdgcn_global_load_lds(
        (const __attribute__((address_space(1))) unsigned int*)g,
        (__attribute__((address_space(3))) unsigned int*)l, 16, 0, 0);
}

// ---- precompute: split x into hi/lo bf16 ----
__global__ __launch_bounds__(256) void split_x_kernel(
    const float* __restrict__ x, u16* __restrict__ xh, u16* __restrict__ xl, int n4)
{
    int idx = blockIdx.x * 256 + threadIdx.x;
    if (idx >= n4) return;
    float4 v = ((const float4*)x)[idx];
    u16x4 hv, lv;
    u16 h, l;
    split2(v.x, h, l); hv.x = h; lv.x = l;
    split2(v.y, h, l); hv.y = h; lv.y = l;
    split2(v.z, h, l); hv.z = h; lv.z = l;
    split2(v.w, h, l); hv.w = h; lv.w = l;
    ((u16x4*)xh)[idx] = hv;
    ((u16x4*)xl)[idx] = lv;
}

// ---- precompute: transpose [R][C] fp32 -> [C][R] hi/lo bf16 ----
__global__ __launch_bounds__(256) void transpose_split(
    const float* __restrict__ src, int R, int C,
    u16* __restrict__ dhi, u16* __restrict__ dlo)
{
    __shared__ float t[32][33];
    int bx = blockIdx.x * 32;
    int by = blockIdx.y * 32;
    int x = threadIdx.x;
    for (int yy = threadIdx.y; yy < 32; yy += 8)
        t[yy][x] = src[(size_t)(by + yy) * C + bx + x];
    __syncthreads();
    for (int i = threadIdx.y; i < 32; i += 8) {
        float v = t[x][i];
        u16 h, l; split2(v, h, l);
        size_t o = (size_t)(bx + i) * R + by + x;
        dhi[o] = h; dlo[o] = l;
    }
}

// ---- precompute: biasT[b][k][q] = mask[b][k] ? bf16(bias[b][q][k]) : -1e30 ----
__global__ __launch_bounds__(256) void bias2t_kernel(
    const float* __restrict__ bias, const int* __restrict__ mask, u16* __restrict__ biasT)
{
    __shared__ float t[64][65];
    const int b = blockIdx.z, k0 = blockIdx.x * 64, q0 = blockIdx.y * 64;
    const int tid = threadIdx.x;
#pragma unroll
    for (int it = 0; it < 16; it++) {
        int idx = it * 256 + tid;
        int qq = idx >> 6, kk = idx & 63;
        t[qq][kk] = bias[((size_t)b * N_ + q0 + qq) * N_ + k0 + kk];
    }
    __syncthreads();
    const u16 NEG = f2bf(-1e30f);
#pragma unroll
    for (int it = 0; it < 16; it++) {
        int idx = it * 256 + tid;
        int kk = idx >> 6, qq = idx & 63;
        int mok = mask[b * N_ + k0 + kk];
        biasT[((size_t)b * N_ + k0 + kk) * N_ + q0 + qq] = mok ? f2bf(t[qq][kk]) : NEG;
    }
}

// ---- stage 1: GEMM x @ [Wq|Wkv]; Q cols 3-term compensated, KV cols 2-term ----
__global__ __launch_bounds__(256) void gemm_qkv(
    const u16* __restrict__ Ah, const u16* __restrict__ Al,
    const u16* __restrict__ Bh, const u16* __restrict__ Bl,
    u16* __restrict__ qh, u16* __restrict__ ql,
    u16* __restrict__ kb, u16* __restrict__ vT)
{
    __shared__ __align__(16) u16 sAh[128 * 32], sAl[128 * 32], sBh[128 * 32], sBl[128 * 32];
    const int tid = threadIdx.x;
    const int wave = tid >> 6, lane = tid & 63;
    const int quad = lane >> 4, l16 = lane & 15;
    const int wm = wave >> 1, wn = wave & 1;
    const int bm = blockIdx.y * 128, bn = blockIdx.x * 128;
    const bool comp = (blockIdx.x < 8);   // Q region: full 3-term compensation

    f32x4 acc[4][4];
#pragma unroll
    for (int i = 0; i < 4; i++)
#pragma unroll
        for (int j = 0; j < 4; j++) acc[i][j] = (f32x4){0.f, 0.f, 0.f, 0.f};

    const int row0 = tid >> 2, g = tid & 3;
    for (int k0 = 0; k0 < 1024; k0 += 32) {
        __syncthreads();
#pragma unroll
        for (int it = 0; it < 2; it++) {
            int row = row0 + it * 64;
            int gc = (g ^ (row & 3)) * 8;
            size_t ga = (size_t)(bm + row) * 1024 + k0 + gc;
            size_t gb = (size_t)(bn + row) * 1024 + k0 + gc;
            int lo = it * 2048 + wave * 512;
            gll16(&Ah[ga], &sAh[lo]);
            gll16(&Al[ga], &sAl[lo]);
            gll16(&Bh[gb], &sBh[lo]);
            if (comp) gll16(&Bl[gb], &sBl[lo]);
        }
        __syncthreads();
        bf16x8 fah[4], fal[4], fbh[4], fbl[4];
#pragma unroll
        for (int s = 0; s < 4; s++) {
            int ra = wm * 64 + s * 16 + l16;
            int rb = wn * 64 + s * 16 + l16;
            int ca = (quad ^ (ra & 3)) * 8;
            int cb = (quad ^ (rb & 3)) * 8;
            fah[s] = *(const bf16x8*)&sAh[ra * 32 + ca];
            fal[s] = *(const bf16x8*)&sAl[ra * 32 + ca];
            fbh[s] = *(const bf16x8*)&sBh[rb * 32 + cb];
            if (comp) fbl[s] = *(const bf16x8*)&sBl[rb * 32 + cb];
        }
#pragma unroll
        for (int sm = 0; sm < 4; sm++)
#pragma unroll
            for (int sn = 0; sn < 4; sn++) {
                acc[sm][sn] = __builtin_amdgcn_mfma_f32_16x16x32_bf16(fah[sm], fbh[sn], acc[sm][sn], 0, 0, 0);
                acc[sm][sn] = __builtin_amdgcn_mfma_f32_16x16x32_bf16(fal[sm], fbh[sn], acc[sm][sn], 0, 0, 0);
                if (comp)
                    acc[sm][sn] = __builtin_amdgcn_mfma_f32_16x16x32_bf16(fah[sm], fbl[sn], acc[sm][sn], 0, 0, 0);
            }
    }
#pragma unroll
    for (int sm = 0; sm < 4; sm++) {
        int rowb = bm + wm * 64 + sm * 16 + quad * 4;
        int bb = rowb >> 11, i0 = rowb & 2047;
#pragma unroll
        for (int sn = 0; sn < 4; sn++) {
            int col = bn + wn * 64 + sn * 16 + l16;
            int region = col >> 10;
            int hh = (col >> 6) & 15;
            int d = col & 63;
            if (region == 0) {
#pragma unroll
                for (int r = 0; r < 4; r++) {
                    float val = acc[sm][sn][r] * SCALE_;
                    u16 a, c; split2(val, a, c);
                    size_t o = (((size_t)(bb * H_ + hh)) * N_ + i0 + r) * DH_ + d;
                    qh[o] = a; ql[o] = c;
                }
            } else if (region == 1) {
#pragma unroll
                for (int r = 0; r < 4; r++) {
                    size_t o = (((size_t)(bb * H_ + hh)) * N_ + i0 + r) * DH_ + d;
                    kb[o] = f2bf(acc[sm][sn][r]);
                }
            } else {
                u16x4 pv;
#pragma unroll
                for (int r = 0; r < 4; r++) pv[r] = f2bf(acc[sm][sn][r]);
                *(u16x4*)&vT[(((size_t)(bb * H_ + hh)) * DH_ + d) * N_ + i0] = pv;
            }
        }
    }
}

// ---- stage 3: O(bf16) @ Wo(hi/lo) + bo -> fp32 ----
__global__ __launch_bounds__(256) void gemm_out(
    const u16* __restrict__ Ab,
    const u16* __restrict__ Bh, const u16* __restrict__ Bl,
    const float* __restrict__ bo, float* __restrict__ out)
{
    __shared__ __align__(16) u16 sA[128 * 32], sBh[128 * 32], sBl[128 * 32];
    const int tid = threadIdx.x;
    const int wave = tid >> 6, lane = tid & 63;
    const int quad = lane >> 4, l16 = lane & 15;
    const int wm = wave >> 1, wn = wave & 1;
    const int bm = blockIdx.y * 128, bn = blockIdx.x * 128;

    f32x4 acc[4][4];
#pragma unroll
    for (int i = 0; i < 4; i++)
#pragma unroll
        for (int j = 0; j < 4; j++) acc[i][j] = (f32x4){0.f, 0.f, 0.f, 0.f};

    const int row0 = tid >> 2, g = tid & 3;
    for (int k0 = 0; k0 < 1024; k0 += 32) {
        __syncthreads();
#pragma unroll
        for (int it = 0; it < 2; it++) {
            int row = row0 + it * 64;
            int gc = (g ^ (row & 3)) * 8;
            size_t ga = (size_t)(bm + row) * 1024 + k0 + gc;
            size_t gb = (size_t)(bn + row) * 1024 + k0 + gc;
            int lo = it * 2048 + wave * 512;
            gll16(&Ab[ga], &sA[lo]);
            gll16(&Bh[gb], &sBh[lo]);
            gll16(&Bl[gb], &sBl[lo]);
        }
        __syncthreads();
        bf16x8 fa[4], fbh[4], fbl[4];
#pragma unroll
        for (int s = 0; s < 4; s++) {
            int ra = wm * 64 + s * 16 + l16;
            int rb = wn * 64 + s * 16 + l16;
            int ca = (quad ^ (ra & 3)) * 8;
            int cb = (quad ^ (rb & 3)) * 8;
            fa[s]  = *(const bf16x8*)&sA[ra * 32 + ca];
            fbh[s] = *(const bf16x8*)&sBh[rb * 32 + cb];
            fbl[s] = *(const bf16x8*)&sBl[rb * 32 + cb];
        }
#pragma unroll
        for (int sm = 0; sm < 4; sm++)
#pragma unroll
            for (int sn = 0; sn < 4; sn++) {
                acc[sm][sn] = __builtin_amdgcn_mfma_f32_16x16x32_bf16(fa[sm], fbh[sn], acc[sm][sn], 0, 0, 0);
                acc[sm][sn] = __builtin_amdgcn_mfma_f32_16x16x32_bf16(fa[sm], fbl[sn], acc[sm][sn], 0, 0, 0);
            }
    }
#pragma unroll
    for (int sm = 0; sm < 4; sm++) {
        int rowb = bm + wm * 64 + sm * 16 + quad * 4;
#pragma unroll
        for (int sn = 0; sn < 4; sn++) {
            int col = bn + wn * 64 + sn * 16 + l16;
            float bv = bo[col];
#pragma unroll
            for (int r = 0; r < 4; r++)
                out[(size_t)(rowb + r) * 1024 + col] = acc[sm][sn][r] + bv;
        }
    }
}

// ---- stage 2: flash attention; keys partitioned across waves ----
// jtile = 128 keys; wave w owns keys [w*32, w*32+32) for all 64 queries.
// l computed via MFMA against all-ones B fragment. Cross-wave O/l reduce at end.
#define LDK 72    // sK  [128 keys][64 d]   stride
#define LDV 136   // sVt [64 d][128 keys]   stride
#define LDB 72    // sBt [128 keys][64 q]   stride (b64 reads, 2-way free)
#define LDP 40    // sP  [4][64 q][32 keys] stride

__global__ __launch_bounds__(256, 2) void attn_kernel(
    const u16* __restrict__ qh, const u16* __restrict__ ql,
    const u16* __restrict__ kb, const u16* __restrict__ vT,
    const u16* __restrict__ biasT, u16* __restrict__ ob)
{
    __shared__ __align__(16) char smem[74752];
    u16* sK  = (u16*)smem;               // 128*72*2  = 18432
    u16* sVt = (u16*)(smem + 18432);     // 64*136*2  = 17408
    u16* sBt = (u16*)(smem + 35840);     // 128*72*2  = 18432
    u16* sP  = (u16*)(smem + 54272);     // 4*64*40*2 = 20480
    float* rO = (float*)smem;            // epilogue alias [4][64][68] f32
    float* rL = (float*)(smem + 69632);  // [4][64] f32

    const int bh = blockIdx.x, b = bh >> 4, h = bh & 15;
    const int qbase = blockIdx.y * 64;
    const int tid = threadIdx.x, wave = tid >> 6, lane = tid & 63;
    const int quad = lane >> 4, l16 = lane & 15;

    // Q A-frags for all 64 queries (pre-scaled by SCALE in gemm_qkv)
    bf16x8 aqh_[4][2], aql_[4][2];
#pragma unroll
    for (int m = 0; m < 4; m++) {
        size_t qo = ((size_t)bh * N_ + qbase + m * 16 + l16) * DH_ + quad * 8;
#pragma unroll
        for (int s = 0; s < 2; s++) {
            aqh_[m][s] = *(const bf16x8*)&qh[qo + s * 32];
            aql_[m][s] = *(const bf16x8*)&ql[qo + s * 32];
        }
    }
    f32x4 Oacc[4][4], lacc[4];
#pragma unroll
    for (int m = 0; m < 4; m++) {
        lacc[m] = (f32x4){0.f, 0.f, 0.f, 0.f};
#pragma unroll
        for (int nd = 0; nd < 4; nd++) Oacc[m][nd] = (f32x4){0.f, 0.f, 0.f, 0.f};
    }
    bf16x8 ones;
#pragma unroll
    for (int i = 0; i < 8; i++) ones[i] = (short)0x3F80;   // bf16 1.0

    const int rK = tid >> 3, cK = (tid & 7) * 8;    // K/B staging: rows +it*32
    const int rV = tid >> 4, cV = (tid & 15) * 8;   // V staging: rows +it*16
    const size_t kgbase = (size_t)bh * N_ * DH_;
    const size_t vgbase = (size_t)bh * DH_ * N_;
    const size_t bgbase = (size_t)b * N_ * N_ + qbase;

    bf16x8 pK[4], pV[4], pB[4];
#pragma unroll
    for (int it = 0; it < 4; it++) {
        pK[it] = *(const bf16x8*)&kb[kgbase + (size_t)(rK + it * 32) * DH_ + cK];
        pV[it] = *(const bf16x8*)&vT[vgbase + (size_t)(rV + it * 16) * N_ + cV];
        pB[it] = *(const bf16x8*)&biasT[bgbase + (size_t)(rK + it * 32) * N_ + cK];
    }

    for (int jt = 0; jt < 16; jt++) {
        // commit staged tile
#pragma unroll
        for (int it = 0; it < 4; it++) {
            *(bf16x8*)&sK[(rK + it * 32) * LDK + cK] = pK[it];
            *(bf16x8*)&sVt[(rV + it * 16) * LDV + cV] = pV[it];
            *(bf16x8*)&sBt[(rK + it * 32) * LDB + cK] = pB[it];
        }
        __syncthreads();
        // prefetch next tile (global latency hidden by compute below)
        {
            int j0n = ((jt + 1) & 15) * 128;
#pragma unroll
            for (int it = 0; it < 4; it++) {
                pK[it] = *(const bf16x8*)&kb[kgbase + (size_t)(j0n + rK + it * 32) * DH_ + cK];
                pV[it] = *(const bf16x8*)&vT[vgbase + (size_t)(rV + it * 16) * N_ + j0n + cV];
                pB[it] = *(const bf16x8*)&biasT[bgbase + (size_t)(j0n + rK + it * 32) * N_ + cK];
            }
        }
        // per-wave frags (shared across all m)
        bf16x8 kf[2][2], vf[4];
#pragma unroll
        for (int n = 0; n < 2; n++)
#pragma unroll
            for (int s = 0; s < 2; s++)
                kf[n][s] = *(const bf16x8*)&sK[(wave * 32 + n * 16 + l16) * LDK + s * 32 + quad * 8];
#pragma unroll
        for (int nd = 0; nd < 4; nd++)
            vf[nd] = *(const bf16x8*)&sVt[(nd * 16 + l16) * LDV + wave * 32 + quad * 8];

#pragma unroll
        for (int m = 0; m < 4; m++) {
            f32x4 S0 = (f32x4){0.f, 0.f, 0.f, 0.f};
            f32x4 S1 = (f32x4){0.f, 0.f, 0.f, 0.f};
#pragma unroll
            for (int s = 0; s < 2; s++) {
                S0 = __builtin_amdgcn_mfma_f32_16x16x32_bf16(aqh_[m][s], kf[0][s], S0, 0, 0, 0);
                S0 = __builtin_amdgcn_mfma_f32_16x16x32_bf16(aql_[m][s], kf[0][s], S0, 0, 0, 0);
                S1 = __builtin_amdgcn_mfma_f32_16x16x32_bf16(aqh_[m][s], kf[1][s], S1, 0, 0, 0);
                S1 = __builtin_amdgcn_mfma_f32_16x16x32_bf16(aql_[m][s], kf[1][s], S1, 0, 0, 0);
            }
            u16x4 b0 = *(const u16x4*)&sBt[(wave * 32 + l16) * LDB + m * 16 + quad * 4];
            u16x4 b1 = *(const u16x4*)&sBt[(wave * 32 + 16 + l16) * LDB + m * 16 + quad * 4];
#pragma unroll
            for (int r = 0; r < 4; r++) {
                S0[r] = __expf(S0[r] + bf2f(b0[r]));
                S1[r] = __expf(S1[r] + bf2f(b1[r]));
            }
            // P: C-layout -> per-wave LDS -> A-layout (same-wave, no barrier)
            u16* pw = sP + (wave * 64 + m * 16 + quad * 4) * LDP;
#pragma unroll
            for (int r = 0; r < 4; r++) {
                pw[r * LDP + l16] = f2bf(S0[r]);
                pw[r * LDP + 16 + l16] = f2bf(S1[r]);
            }
            bf16x8 pa = *(const bf16x8*)&sP[(wave * 64 + m * 16 + l16) * LDP + quad * 8];
            lacc[m] = __builtin_amdgcn_mfma_f32_16x16x32_bf16(pa, ones, lacc[m], 0, 0, 0);
#pragma unroll
            for (int nd = 0; nd < 4; nd++)
                Oacc[m][nd] = __builtin_amdgcn_mfma_f32_16x16x32_bf16(pa, vf[nd], Oacc[m][nd], 0, 0, 0);
        }
        __syncthreads();
    }

    // cross-wave reduction of O and l partials through LDS
#pragma unroll
    for (int m = 0; m < 4; m++)
#pragma unroll
        for (int nd = 0; nd < 4; nd++)
#pragma unroll
            for (int r = 0; r < 4; r++)
                rO[(wave * 64 + m * 16 + quad * 4 + r) * 68 + nd * 16 + l16] = Oacc[m][nd][r];
    if (l16 == 0) {
#pragma unroll
        for (int m = 0; m < 4; m++)
#pragma unroll
            for (int r = 0; r < 4; r++)
                rL[wave * 64 + m * 16 + quad * 4 + r] = lacc[m][r];
    }
    __syncthreads();
    {
        const int q = tid >> 2, dg = (tid & 3) * 16;
        float l = rL[q] + rL[64 + q] + rL[128 + q] + rL[192 + q];
        float inv = 1.f / l;
        f32x4 s[4];
#pragma unroll
        for (int i4 = 0; i4 < 4; i4++) s[i4] = *(const f32x4*)&rO[(size_t)q * 68 + dg + i4 * 4];
#pragma unroll
        for (int w = 1; w < 4; w++)
#pragma unroll
            for (int i4 = 0; i4 < 4; i4++) {
                f32x4 v = *(const f32x4*)&rO[(size_t)(w * 64 + q) * 68 + dg + i4 * 4];
                s[i4] += v;
            }
        size_t obase = ((size_t)b * N_ + qbase + q) * INNER_ + h * 64 + dg;
#pragma unroll
        for (int i4 = 0; i4 < 4; i4++) {
            u16x4 o4;
#pragma unroll
            for (int r = 0; r < 4; r++) o4[r] = f2bf(s[i4][r] * inv);
            *(u16x4*)&ob[obase + i4 * 4] = o4;
        }
    }
}

extern "C" void kernel_launch(void* const* d_in, const int* in_sizes, int n_in,
                              void* d_out, int out_size, void* d_ws, size_t ws_size,
                              hipStream_t stream)
{
    const float* x    = (const float*)d_in[0];
    const float* bias = (const float*)d_in[1];
    const int*   mask = (const int*)d_in[2];
    const float* Wq   = (const float*)d_in[3];
    const float* Wkv  = (const float*)d_in[4];
    const float* Wo   = (const float*)d_in[5];
    const float* bo   = (const float*)d_in[6];
    float* out = (float*)d_out;

    char* w = (char*)d_ws;
    const size_t MB = 1024 * 1024;
    u16* q_h   = (u16*)(w);             //  0..8   [32][2048][64]
    u16* q_l   = (u16*)(w + 8 * MB);    //  8..16
    u16* k_b   = (u16*)(w + 16 * MB);   // 16..24
    u16* v_T   = (u16*)(w + 24 * MB);   // 24..32  [32][64][2048]
    u16* xs_h  = (u16*)(w + 32 * MB);   // dead after gemm_qkv
    u16* xs_l  = (u16*)(w + 40 * MB);   // dead after gemm_qkv
    u16* biasT = (u16*)(w + 32 * MB);   // 32..48.8 (written after gemm_qkv; overlaps dead xs/wT head)
    u16* wT_h  = (u16*)(w + 48 * MB);   // dead after gemm_qkv
    u16* wT_l  = (u16*)(w + 54 * MB);
    u16* woT_h = (u16*)(w + 60 * MB);
    u16* woT_l = (u16*)(w + 62 * MB);
    u16* o_b   = (u16*)(w + 64 * MB);   // 64..72  [2][2048][1024]

    dim3 tb(32, 8);
    split_x_kernel<<<4096, 256, 0, stream>>>(x, xs_h, xs_l, (B_ * N_ * QD_) / 4);
    transpose_split<<<dim3(32, 32), tb, 0, stream>>>(Wq, 1024, 1024, wT_h, wT_l);
    transpose_split<<<dim3(64, 32), tb, 0, stream>>>(Wkv, 1024, 2048, wT_h + 1024 * 1024, wT_l + 1024 * 1024);
    transpose_split<<<dim3(32, 32), tb, 0, stream>>>(Wo, 1024, 1024, woT_h, woT_l);

    gemm_qkv<<<dim3(24, 32), 256, 0, stream>>>(xs_h, xs_l, wT_h, wT_l, q_h, q_l, k_b, v_T);
    bias2t_kernel<<<dim3(32, 32, 2), 256, 0, stream>>>(bias, mask, biasT);
    attn_kernel<<<dim3(32, 32), 256, 0, stream>>>(q_h, q_l, k_b, v_T, biasT, o_b);
    gemm_out<<<dim3(8, 32), 256, 0, stream>>>(o_b, woT_h, woT_l, bo, out);
}

// Round 5
// 327.245 us; speedup vs baseline: 2.1577x; 1.0419x over previous
//
#include <hip/hip_runtime.h>
#include <stdint.h>

#define B_     2
#define N_     2048
#define QD_    1024
#define H_     16
#define DH_    64
#define INNER_ 1024
#define SCALE_ 0.125f

typedef unsigned short u16;
typedef __attribute__((ext_vector_type(8))) short bf16x8;   // 8 bf16 = 4 VGPRs
typedef __attribute__((ext_vector_type(4))) float f32x4;    // MFMA C/D frag
typedef __attribute__((ext_vector_type(4))) unsigned short u16x4;

// ---- bf16 helpers (RNE) ----
__device__ inline u16 f2bf(float f) {
    union { float f; uint32_t u; } c; c.f = f;
    uint32_t r = c.u + 0x7FFFu + ((c.u >> 16) & 1u);
    return (u16)(r >> 16);
}
__device__ inline float bf2f(u16 s) {
    union { uint32_t u; float f; } c; c.u = ((uint32_t)s) << 16;
    return c.f;
}
__device__ inline void split2(float v, u16 &h, u16 &l) {
    u16 hs = f2bf(v);
    h = hs;
    l = f2bf(v - bf2f(hs));
}

// ---- prep: split_x (blocks 0..4095) + W transposes (blocks 4096..8191) ----
__global__ __launch_bounds__(256) void prep_kernel(
    const float* __restrict__ x, u16* __restrict__ xh, u16* __restrict__ xl,
    const float* __restrict__ Wq, const float* __restrict__ Wkv, const float* __restrict__ Wo,
    u16* __restrict__ wTh, u16* __restrict__ wTl,
    u16* __restrict__ woTh, u16* __restrict__ woTl)
{
    __shared__ float t[32][33];
    const int blk = blockIdx.x, tid = threadIdx.x;
    if (blk < 4096) {
        int idx = blk * 256 + tid;
        float4 v = ((const float4*)x)[idx];
        u16x4 hv, lv; u16 h, l;
        split2(v.x, h, l); hv.x = h; lv.x = l;
        split2(v.y, h, l); hv.y = h; lv.y = l;
        split2(v.z, h, l); hv.z = h; lv.z = l;
        split2(v.w, h, l); hv.w = h; lv.w = l;
        ((u16x4*)xh)[idx] = hv;
        ((u16x4*)xl)[idx] = lv;
        return;
    }
    int local = blk - 4096;
    const float* src; u16 *dhi, *dlo; int C, bx, by;
    if (local < 1024)      { src = Wq;  dhi = wTh;                dlo = wTl;                C = 1024; by = local >> 5; bx = local & 31; }
    else if (local < 3072) { int l2 = local - 1024; src = Wkv; dhi = wTh + 1024 * 1024; dlo = wTl + 1024 * 1024; C = 2048; by = l2 >> 6; bx = l2 & 63; }
    else                   { int l2 = local - 3072; src = Wo;  dhi = woTh;               dlo = woTl;               C = 1024; by = l2 >> 5; bx = l2 & 31; }
    const int x0 = bx * 32, y0 = by * 32;
    const int tx = tid & 31, ty = tid >> 5;
    for (int yy = ty; yy < 32; yy += 8)
        t[yy][tx] = src[(size_t)(y0 + yy) * C + x0 + tx];
    __syncthreads();
    for (int i = ty; i < 32; i += 8) {
        float v = t[tx][i];                        // src[y0+tx][x0+i]
        u16 h, l; split2(v, h, l);
        size_t o = (size_t)(x0 + i) * 1024 + y0 + tx;  // dst rows = src cols; R=1024
        dhi[o] = h; dlo[o] = l;
    }
}

// ---- stage 1: GEMM x @ [Wq|Wkv] (register-prefetch pipeline) + co-scheduled
// bias/mask transpose blocks. mode: 0=gemm only, 1=interleaved 3:8, 2=bias only.
// LDS swizzle: slot s of row r holds global K-group s^(r&3).
// Thread (r=tid>>2, g=tid&3) loads group g^(r&3) -> writes LDS slot g (offset r*32+g*8).
// Frag read of group `quad` for row ra: slot quad^(ra&3).
__global__ __launch_bounds__(256) void gemm_qkv_bias(
    int mode,
    const u16* __restrict__ Ah, const u16* __restrict__ Al,
    const u16* __restrict__ Bh, const u16* __restrict__ Bl,
    u16* __restrict__ qh, u16* __restrict__ ql,
    u16* __restrict__ kb, u16* __restrict__ vT,
    const float* __restrict__ bias, const int* __restrict__ mask,
    u16* __restrict__ biasT)
{
    __shared__ __align__(16) char smem[32768];
    const int tid = threadIdx.x;

    int gid = -1, bid = -1;
    if (mode == 1) {
        int grp = blockIdx.x / 11, r = blockIdx.x % 11;
        if (r < 3) gid = grp * 3 + r; else bid = grp * 8 + (r - 3);
    } else if (mode == 0) gid = blockIdx.x;
    else bid = blockIdx.x;

    if (bid >= 0) {
        // ---- bias path: biasT[b][k][q] = mask ? bf16(bias[b][q][k]) : -1e30 ----
        float (*t)[65] = (float(*)[65])smem;
        const int b = bid >> 10, rest = bid & 1023;
        const int k0 = (rest & 31) * 64, q0 = (rest >> 5) * 64;
#pragma unroll
        for (int it = 0; it < 16; it++) {
            int idx = it * 256 + tid;
            int qq = idx >> 6, kk = idx & 63;
            t[qq][kk] = bias[((size_t)b * N_ + q0 + qq) * N_ + k0 + kk];
        }
        __syncthreads();
        const u16 NEG = f2bf(-1e30f);
#pragma unroll
        for (int it = 0; it < 16; it++) {
            int idx = it * 256 + tid;
            int kk = idx >> 6, qq = idx & 63;
            int mok = mask[b * N_ + k0 + kk];
            biasT[((size_t)b * N_ + k0 + kk) * N_ + q0 + qq] = mok ? f2bf(t[qq][kk]) : NEG;
        }
        return;
    }

    // ---- gemm path ----
    u16* sAh = (u16*)smem;
    u16* sAl = (u16*)(smem + 8192);
    u16* sBh = (u16*)(smem + 16384);
    u16* sBl = (u16*)(smem + 24576);
    const int wave = tid >> 6, lane = tid & 63;
    const int quad = lane >> 4, l16 = lane & 15;
    const int wm = wave >> 1, wn = wave & 1;
    const int bx = gid % 24, by = gid / 24;
    const int bm = by * 128, bn = bx * 128;
    const bool comp = (bx < 8);   // Q columns: 3-term compensation

    f32x4 acc[4][4];
#pragma unroll
    for (int i = 0; i < 4; i++)
#pragma unroll
        for (int j = 0; j < 4; j++) acc[i][j] = (f32x4){0.f, 0.f, 0.f, 0.f};

    const int row0 = tid >> 2, g4 = tid & 3;
    const int r1 = row0, r2 = row0 + 64;
    const int gc1 = (g4 ^ (r1 & 3)) * 8, gc2 = (g4 ^ (r2 & 3)) * 8;
    const size_t a1 = (size_t)(bm + r1) * 1024 + gc1, a2 = (size_t)(bm + r2) * 1024 + gc2;
    const size_t b1 = (size_t)(bn + r1) * 1024 + gc1, b2 = (size_t)(bn + r2) * 1024 + gc2;
    const int w1 = r1 * 32 + g4 * 8, w2 = r2 * 32 + g4 * 8;   // slot index = g4 (data group g4^(r&3))

    bf16x8 pAh0, pAh1, pAl0, pAl1, pBh0, pBh1, pBl0, pBl1;
    pAh0 = *(const bf16x8*)&Ah[a1]; pAh1 = *(const bf16x8*)&Ah[a2];
    pAl0 = *(const bf16x8*)&Al[a1]; pAl1 = *(const bf16x8*)&Al[a2];
    pBh0 = *(const bf16x8*)&Bh[b1]; pBh1 = *(const bf16x8*)&Bh[b2];
    if (comp) { pBl0 = *(const bf16x8*)&Bl[b1]; pBl1 = *(const bf16x8*)&Bl[b2]; }

    for (int k0 = 0; k0 < 1024; k0 += 32) {
        // commit prefetched tile to LDS
        *(bf16x8*)&sAh[w1] = pAh0; *(bf16x8*)&sAh[w2] = pAh1;
        *(bf16x8*)&sAl[w1] = pAl0; *(bf16x8*)&sAl[w2] = pAl1;
        *(bf16x8*)&sBh[w1] = pBh0; *(bf16x8*)&sBh[w2] = pBh1;
        if (comp) { *(bf16x8*)&sBl[w1] = pBl0; *(bf16x8*)&sBl[w2] = pBl1; }
        __syncthreads();
        // prefetch next tile (drains during MFMA phase)
        if (k0 + 32 < 1024) {
            int kn = k0 + 32;
            pAh0 = *(const bf16x8*)&Ah[a1 + kn]; pAh1 = *(const bf16x8*)&Ah[a2 + kn];
            pAl0 = *(const bf16x8*)&Al[a1 + kn]; pAl1 = *(const bf16x8*)&Al[a2 + kn];
            pBh0 = *(const bf16x8*)&Bh[b1 + kn]; pBh1 = *(const bf16x8*)&Bh[b2 + kn];
            if (comp) { pBl0 = *(const bf16x8*)&Bl[b1 + kn]; pBl1 = *(const bf16x8*)&Bl[b2 + kn]; }
        }
        bf16x8 fah[4], fal[4], fbh[4], fbl[4];
#pragma unroll
        for (int s = 0; s < 4; s++) {
            int ra = wm * 64 + s * 16 + l16;
            int rb = wn * 64 + s * 16 + l16;
            int ca = (quad ^ (ra & 3)) * 8;
            int cb = (quad ^ (rb & 3)) * 8;
            fah[s] = *(const bf16x8*)&sAh[ra * 32 + ca];
            fal[s] = *(const bf16x8*)&sAl[ra * 32 + ca];
            fbh[s] = *(const bf16x8*)&sBh[rb * 32 + cb];
            if (comp) fbl[s] = *(const bf16x8*)&sBl[rb * 32 + cb];
        }
#pragma unroll
        for (int sm = 0; sm < 4; sm++)
#pragma unroll
            for (int sn = 0; sn < 4; sn++) {
                acc[sm][sn] = __builtin_amdgcn_mfma_f32_16x16x32_bf16(fah[sm], fbh[sn], acc[sm][sn], 0, 0, 0);
                acc[sm][sn] = __builtin_amdgcn_mfma_f32_16x16x32_bf16(fal[sm], fbh[sn], acc[sm][sn], 0, 0, 0);
                if (comp)
                    acc[sm][sn] = __builtin_amdgcn_mfma_f32_16x16x32_bf16(fah[sm], fbl[sn], acc[sm][sn], 0, 0, 0);
            }
        __syncthreads();
    }
#pragma unroll
    for (int sm = 0; sm < 4; sm++) {
        int rowb = bm + wm * 64 + sm * 16 + quad * 4;
        int bb = rowb >> 11, i0 = rowb & 2047;
#pragma unroll
        for (int sn = 0; sn < 4; sn++) {
            int col = bn + wn * 64 + sn * 16 + l16;
            int region = col >> 10;
            int hh = (col >> 6) & 15;
            int d = col & 63;
            if (region == 0) {
#pragma unroll
                for (int r = 0; r < 4; r++) {
                    float val = acc[sm][sn][r] * SCALE_;
                    u16 a, c; split2(val, a, c);
                    size_t o = (((size_t)(bb * H_ + hh)) * N_ + i0 + r) * DH_ + d;
                    qh[o] = a; ql[o] = c;
                }
            } else if (region == 1) {
#pragma unroll
                for (int r = 0; r < 4; r++) {
                    size_t o = (((size_t)(bb * H_ + hh)) * N_ + i0 + r) * DH_ + d;
                    kb[o] = f2bf(acc[sm][sn][r]);
                }
            } else {
                u16x4 pv;
#pragma unroll
                for (int r = 0; r < 4; r++) pv[r] = f2bf(acc[sm][sn][r]);
                *(u16x4*)&vT[(((size_t)(bb * H_ + hh)) * DH_ + d) * N_ + i0] = pv;
            }
        }
    }
}

// ---- stage 3: O(bf16) @ Wo(hi/lo) + bo -> fp32 (register-prefetch pipeline) ----
__global__ __launch_bounds__(256) void gemm_out(
    const u16* __restrict__ Ab,
    const u16* __restrict__ Bh, const u16* __restrict__ Bl,
    const float* __restrict__ bo, float* __restrict__ out)
{
    __shared__ __align__(16) u16 sA[128 * 32], sBh[128 * 32], sBl[128 * 32];
    const int tid = threadIdx.x;
    const int wave = tid >> 6, lane = tid & 63;
    const int quad = lane >> 4, l16 = lane & 15;
    const int wm = wave >> 1, wn = wave & 1;
    const int bm = blockIdx.y * 128, bn = blockIdx.x * 128;

    f32x4 acc[4][4];
#pragma unroll
    for (int i = 0; i < 4; i++)
#pragma unroll
        for (int j = 0; j < 4; j++) acc[i][j] = (f32x4){0.f, 0.f, 0.f, 0.f};

    const int row0 = tid >> 2, g4 = tid & 3;
    const int r1 = row0, r2 = row0 + 64;
    const int gc1 = (g4 ^ (r1 & 3)) * 8, gc2 = (g4 ^ (r2 & 3)) * 8;
    const size_t a1 = (size_t)(bm + r1) * 1024 + gc1, a2 = (size_t)(bm + r2) * 1024 + gc2;
    const size_t b1 = (size_t)(bn + r1) * 1024 + gc1, b2 = (size_t)(bn + r2) * 1024 + gc2;
    const int w1 = r1 * 32 + g4 * 8, w2 = r2 * 32 + g4 * 8;   // slot index = g4

    bf16x8 pA0, pA1, pBh0, pBh1, pBl0, pBl1;
    pA0 = *(const bf16x8*)&Ab[a1]; pA1 = *(const bf16x8*)&Ab[a2];
    pBh0 = *(const bf16x8*)&Bh[b1]; pBh1 = *(const bf16x8*)&Bh[b2];
    pBl0 = *(const bf16x8*)&Bl[b1]; pBl1 = *(const bf16x8*)&Bl[b2];

    for (int k0 = 0; k0 < 1024; k0 += 32) {
        *(bf16x8*)&sA[w1] = pA0;  *(bf16x8*)&sA[w2] = pA1;
        *(bf16x8*)&sBh[w1] = pBh0; *(bf16x8*)&sBh[w2] = pBh1;
        *(bf16x8*)&sBl[w1] = pBl0; *(bf16x8*)&sBl[w2] = pBl1;
        __syncthreads();
        if (k0 + 32 < 1024) {
            int kn = k0 + 32;
            pA0 = *(const bf16x8*)&Ab[a1 + kn]; pA1 = *(const bf16x8*)&Ab[a2 + kn];
            pBh0 = *(const bf16x8*)&Bh[b1 + kn]; pBh1 = *(const bf16x8*)&Bh[b2 + kn];
            pBl0 = *(const bf16x8*)&Bl[b1 + kn]; pBl1 = *(const bf16x8*)&Bl[b2 + kn];
        }
        bf16x8 fa[4], fbh[4], fbl[4];
#pragma unroll
        for (int s = 0; s < 4; s++) {
            int ra = wm * 64 + s * 16 + l16;
            int rb = wn * 64 + s * 16 + l16;
            int ca = (quad ^ (ra & 3)) * 8;
            int cb = (quad ^ (rb & 3)) * 8;
            fa[s]  = *(const bf16x8*)&sA[ra * 32 + ca];
            fbh[s] = *(const bf16x8*)&sBh[rb * 32 + cb];
            fbl[s] = *(const bf16x8*)&sBl[rb * 32 + cb];
        }
#pragma unroll
        for (int sm = 0; sm < 4; sm++)
#pragma unroll
            for (int sn = 0; sn < 4; sn++) {
                acc[sm][sn] = __builtin_amdgcn_mfma_f32_16x16x32_bf16(fa[sm], fbh[sn], acc[sm][sn], 0, 0, 0);
                acc[sm][sn] = __builtin_amdgcn_mfma_f32_16x16x32_bf16(fa[sm], fbl[sn], acc[sm][sn], 0, 0, 0);
            }
        __syncthreads();
    }
#pragma unroll
    for (int sm = 0; sm < 4; sm++) {
        int rowb = bm + wm * 64 + sm * 16 + quad * 4;
#pragma unroll
        for (int sn = 0; sn < 4; sn++) {
            int col = bn + wn * 64 + sn * 16 + l16;
            float bv = bo[col];
#pragma unroll
            for (int r = 0; r < 4; r++)
                out[(size_t)(rowb + r) * 1024 + col] = acc[sm][sn][r] + bv;
        }
    }
}

// ---- stage 2: flash attention; keys partitioned across waves ----
#define LDK 72    // sK  [128 keys][64 d]   stride
#define LDV 136   // sVt [64 d][128 keys]   stride
#define LDB 72    // sBt [128 keys][64 q]   stride
#define LDP 40    // sP  [4][64 q][32 keys] stride

__global__ __launch_bounds__(256, 2) void attn_kernel(
    const u16* __restrict__ qh, const u16* __restrict__ ql,
    const u16* __restrict__ kb, const u16* __restrict__ vT,
    const u16* __restrict__ biasT, u16* __restrict__ ob)
{
    __shared__ __align__(16) char smem[74752];
    u16* sK  = (u16*)smem;               // 128*72*2  = 18432
    u16* sVt = (u16*)(smem + 18432);     // 64*136*2  = 17408
    u16* sBt = (u16*)(smem + 35840);     // 128*72*2  = 18432
    u16* sP  = (u16*)(smem + 54272);     // 4*64*40*2 = 20480
    float* rO = (float*)smem;            // epilogue alias [4][64][68] f32
    float* rL = (float*)(smem + 69632);  // [4][64] f32

    const int bh = blockIdx.x, b = bh >> 4, h = bh & 15;
    const int qbase = blockIdx.y * 64;
    const int tid = threadIdx.x, wave = tid >> 6, lane = tid & 63;
    const int quad = lane >> 4, l16 = lane & 15;

    bf16x8 aqh_[4][2], aql_[4][2];
#pragma unroll
    for (int m = 0; m < 4; m++) {
        size_t qo = ((size_t)bh * N_ + qbase + m * 16 + l16) * DH_ + quad * 8;
#pragma unroll
        for (int s = 0; s < 2; s++) {
            aqh_[m][s] = *(const bf16x8*)&qh[qo + s * 32];
            aql_[m][s] = *(const bf16x8*)&ql[qo + s * 32];
        }
    }
    f32x4 Oacc[4][4], lacc[4];
#pragma unroll
    for (int m = 0; m < 4; m++) {
        lacc[m] = (f32x4){0.f, 0.f, 0.f, 0.f};
#pragma unroll
        for (int nd = 0; nd < 4; nd++) Oacc[m][nd] = (f32x4){0.f, 0.f, 0.f, 0.f};
    }
    bf16x8 ones;
#pragma unroll
    for (int i = 0; i < 8; i++) ones[i] = (short)0x3F80;

    const int rK = tid >> 3, cK = (tid & 7) * 8;
    const int rV = tid >> 4, cV = (tid & 15) * 8;
    const size_t kgbase = (size_t)bh * N_ * DH_;
    const size_t vgbase = (size_t)bh * DH_ * N_;
    const size_t bgbase = (size_t)b * N_ * N_ + qbase;

    bf16x8 pK[4], pV[4], pB[4];
#pragma unroll
    for (int it = 0; it < 4; it++) {
        pK[it] = *(const bf16x8*)&kb[kgbase + (size_t)(rK + it * 32) * DH_ + cK];
        pV[it] = *(const bf16x8*)&vT[vgbase + (size_t)(rV + it * 16) * N_ + cV];
        pB[it] = *(const bf16x8*)&biasT[bgbase + (size_t)(rK + it * 32) * N_ + cK];
    }

    for (int jt = 0; jt < 16; jt++) {
#pragma unroll
        for (int it = 0; it < 4; it++) {
            *(bf16x8*)&sK[(rK + it * 32) * LDK + cK] = pK[it];
            *(bf16x8*)&sVt[(rV + it * 16) * LDV + cV] = pV[it];
            *(bf16x8*)&sBt[(rK + it * 32) * LDB + cK] = pB[it];
        }
        __syncthreads();
        {
            int j0n = ((jt + 1) & 15) * 128;
#pragma unroll
            for (int it = 0; it < 4; it++) {
                pK[it] = *(const bf16x8*)&kb[kgbase + (size_t)(j0n + rK + it * 32) * DH_ + cK];
                pV[it] = *(const bf16x8*)&vT[vgbase + (size_t)(rV + it * 16) * N_ + j0n + cV];
                pB[it] = *(const bf16x8*)&biasT[bgbase + (size_t)(j0n + rK + it * 32) * N_ + cK];
            }
        }
        bf16x8 kf[2][2], vf[4];
#pragma unroll
        for (int n = 0; n < 2; n++)
#pragma unroll
            for (int s = 0; s < 2; s++)
                kf[n][s] = *(const bf16x8*)&sK[(wave * 32 + n * 16 + l16) * LDK + s * 32 + quad * 8];
#pragma unroll
        for (int nd = 0; nd < 4; nd++)
            vf[nd] = *(const bf16x8*)&sVt[(nd * 16 + l16) * LDV + wave * 32 + quad * 8];

#pragma unroll
        for (int m = 0; m < 4; m++) {
            f32x4 S0 = (f32x4){0.f, 0.f, 0.f, 0.f};
            f32x4 S1 = (f32x4){0.f, 0.f, 0.f, 0.f};
#pragma unroll
            for (int s = 0; s < 2; s++) {
                S0 = __builtin_amdgcn_mfma_f32_16x16x32_bf16(aqh_[m][s], kf[0][s], S0, 0, 0, 0);
                S0 = __builtin_amdgcn_mfma_f32_16x16x32_bf16(aql_[m][s], kf[0][s], S0, 0, 0, 0);
                S1 = __builtin_amdgcn_mfma_f32_16x16x32_bf16(aqh_[m][s], kf[1][s], S1, 0, 0, 0);
                S1 = __builtin_amdgcn_mfma_f32_16x16x32_bf16(aql_[m][s], kf[1][s], S1, 0, 0, 0);
            }
            u16x4 b0 = *(const u16x4*)&sBt[(wave * 32 + l16) * LDB + m * 16 + quad * 4];
            u16x4 b1 = *(const u16x4*)&sBt[(wave * 32 + 16 + l16) * LDB + m * 16 + quad * 4];
#pragma unroll
            for (int r = 0; r < 4; r++) {
                S0[r] = __expf(S0[r] + bf2f(b0[r]));
                S1[r] = __expf(S1[r] + bf2f(b1[r]));
            }
            u16* pw = sP + (wave * 64 + m * 16 + quad * 4) * LDP;
#pragma unroll
            for (int r = 0; r < 4; r++) {
                pw[r * LDP + l16] = f2bf(S0[r]);
                pw[r * LDP + 16 + l16] = f2bf(S1[r]);
            }
            bf16x8 pa = *(const bf16x8*)&sP[(wave * 64 + m * 16 + l16) * LDP + quad * 8];
            lacc[m] = __builtin_amdgcn_mfma_f32_16x16x32_bf16(pa, ones, lacc[m], 0, 0, 0);
#pragma unroll
            for (int nd = 0; nd < 4; nd++)
                Oacc[m][nd] = __builtin_amdgcn_mfma_f32_16x16x32_bf16(pa, vf[nd], Oacc[m][nd], 0, 0, 0);
        }
        __syncthreads();
    }

#pragma unroll
    for (int m = 0; m < 4; m++)
#pragma unroll
        for (int nd = 0; nd < 4; nd++)
#pragma unroll
            for (int r = 0; r < 4; r++)
                rO[(wave * 64 + m * 16 + quad * 4 + r) * 68 + nd * 16 + l16] = Oacc[m][nd][r];
    if (l16 == 0) {
#pragma unroll
        for (int m = 0; m < 4; m++)
#pragma unroll
            for (int r = 0; r < 4; r++)
                rL[wave * 64 + m * 16 + quad * 4 + r] = lacc[m][r];
    }
    __syncthreads();
    {
        const int q = tid >> 2, dg = (tid & 3) * 16;
        float l = rL[q] + rL[64 + q] + rL[128 + q] + rL[192 + q];
        float inv = 1.f / l;
        f32x4 s[4];
#pragma unroll
        for (int i4 = 0; i4 < 4; i4++) s[i4] = *(const f32x4*)&rO[(size_t)q * 68 + dg + i4 * 4];
#pragma unroll
        for (int w = 1; w < 4; w++)
#pragma unroll
            for (int i4 = 0; i4 < 4; i4++) {
                f32x4 v = *(const f32x4*)&rO[(size_t)(w * 64 + q) * 68 + dg + i4 * 4];
                s[i4] += v;
            }
        size_t obase = ((size_t)b * N_ + qbase + q) * INNER_ + h * 64 + dg;
#pragma unroll
        for (int i4 = 0; i4 < 4; i4++) {
            u16x4 o4;
#pragma unroll
            for (int r = 0; r < 4; r++) o4[r] = f2bf(s[i4][r] * inv);
            *(u16x4*)&ob[obase + i4 * 4] = o4;
        }
    }
}

extern "C" void kernel_launch(void* const* d_in, const int* in_sizes, int n_in,
                              void* d_out, int out_size, void* d_ws, size_t ws_size,
                              hipStream_t stream)
{
    const float* x    = (const float*)d_in[0];
    const float* bias = (const float*)d_in[1];
    const int*   mask = (const int*)d_in[2];
    const float* Wq   = (const float*)d_in[3];
    const float* Wkv  = (const float*)d_in[4];
    const float* Wo   = (const float*)d_in[5];
    const float* bo   = (const float*)d_in[6];
    float* out = (float*)d_out;

    char* w = (char*)d_ws;
    const size_t MB = 1024 * 1024;
    u16* q_h   = (u16*)(w);             //  0..8   [32][2048][64]
    u16* q_l   = (u16*)(w + 8 * MB);
    u16* k_b   = (u16*)(w + 16 * MB);
    u16* v_T   = (u16*)(w + 24 * MB);   // [32][64][2048]
    u16* xs_h  = (u16*)(w + 32 * MB);
    u16* xs_l  = (u16*)(w + 40 * MB);
    u16* wT_h  = (u16*)(w + 48 * MB);   // [3072][1024]
    u16* wT_l  = (u16*)(w + 54 * MB);
    u16* woT_h = (u16*)(w + 60 * MB);
    u16* woT_l = (u16*)(w + 62 * MB);
    u16* o_b   = (u16*)(w + 64 * MB);   // [2][2048][1024]

    const size_t biasT_bytes = (size_t)2 * N_ * N_ * sizeof(u16);   // 16.78 MB
    const bool concurrent = ws_size >= 72 * MB + biasT_bytes;

    prep_kernel<<<8192, 256, 0, stream>>>(x, xs_h, xs_l, Wq, Wkv, Wo, wT_h, wT_l, woT_h, woT_l);

    if (concurrent) {
        u16* biasT = (u16*)(w + 72 * MB);   // disjoint: safe alongside gemm reads
        gemm_qkv_bias<<<2816, 256, 0, stream>>>(1, xs_h, xs_l, wT_h, wT_l,
                                                q_h, q_l, k_b, v_T, bias, mask, biasT);
        attn_kernel<<<dim3(32, 32), 256, 0, stream>>>(q_h, q_l, k_b, v_T, biasT, o_b);
    } else {
        u16* biasT = (u16*)(w + 32 * MB);   // aliases xs (dead after gemm) — sequential only
        gemm_qkv_bias<<<768, 256, 0, stream>>>(0, xs_h, xs_l, wT_h, wT_l,
                                               q_h, q_l, k_b, v_T, bias, mask, biasT);
        gemm_qkv_bias<<<2048, 256, 0, stream>>>(2, xs_h, xs_l, wT_h, wT_l,
                                                q_h, q_l, k_b, v_T, bias, mask, biasT);
        attn_kernel<<<dim3(32, 32), 256, 0, stream>>>(q_h, q_l, k_b, v_T, biasT, o_b);
    }
    gemm_out<<<dim3(8, 32), 256, 0, stream>>>(o_b, woT_h, woT_l, bo, out);
}

// Round 6
// 296.407 us; speedup vs baseline: 2.3822x; 1.1040x over previous
//
#include <hip/hip_runtime.h>
#include <stdint.h>

#define B_     2
#define N_     2048
#define QD_    1024
#define H_     16
#define DH_    64
#define INNER_ 1024
#define SCALE_ 0.125f

typedef unsigned short u16;
typedef __attribute__((ext_vector_type(8))) short bf16x8;   // 8 bf16 = 4 VGPRs
typedef __attribute__((ext_vector_type(4))) float f32x4;    // MFMA C/D frag
typedef __attribute__((ext_vector_type(4))) unsigned short u16x4;

// ---- bf16 helpers (RNE) ----
__device__ inline u16 f2bf(float f) {
    union { float f; uint32_t u; } c; c.f = f;
    uint32_t r = c.u + 0x7FFFu + ((c.u >> 16) & 1u);
    return (u16)(r >> 16);
}
__device__ inline float bf2f(u16 s) {
    union { uint32_t u; float f; } c; c.u = ((uint32_t)s) << 16;
    return c.f;
}
__device__ inline void split2(float v, u16 &h, u16 &l) {
    u16 hs = f2bf(v);
    h = hs;
    l = f2bf(v - bf2f(hs));
}

// ---- prep: split_x (blocks 0..4095) + W transposes (blocks 4096..8191) ----
__global__ __launch_bounds__(256) void prep_kernel(
    const float* __restrict__ x, u16* __restrict__ xh, u16* __restrict__ xl,
    const float* __restrict__ Wq, const float* __restrict__ Wkv, const float* __restrict__ Wo,
    u16* __restrict__ wTh, u16* __restrict__ wTl,
    u16* __restrict__ woTh, u16* __restrict__ woTl)
{
    __shared__ float t[32][33];
    const int blk = blockIdx.x, tid = threadIdx.x;
    if (blk < 4096) {
        int idx = blk * 256 + tid;
        float4 v = ((const float4*)x)[idx];
        u16x4 hv, lv; u16 h, l;
        split2(v.x, h, l); hv.x = h; lv.x = l;
        split2(v.y, h, l); hv.y = h; lv.y = l;
        split2(v.z, h, l); hv.z = h; lv.z = l;
        split2(v.w, h, l); hv.w = h; lv.w = l;
        ((u16x4*)xh)[idx] = hv;
        ((u16x4*)xl)[idx] = lv;
        return;
    }
    int local = blk - 4096;
    const float* src; u16 *dhi, *dlo; int C, bx, by;
    if (local < 1024)      { src = Wq;  dhi = wTh;                dlo = wTl;                C = 1024; by = local >> 5; bx = local & 31; }
    else if (local < 3072) { int l2 = local - 1024; src = Wkv; dhi = wTh + 1024 * 1024; dlo = wTl + 1024 * 1024; C = 2048; by = l2 >> 6; bx = l2 & 63; }
    else                   { int l2 = local - 3072; src = Wo;  dhi = woTh;               dlo = woTl;               C = 1024; by = l2 >> 5; bx = l2 & 31; }
    const int x0 = bx * 32, y0 = by * 32;
    const int tx = tid & 31, ty = tid >> 5;
    for (int yy = ty; yy < 32; yy += 8)
        t[yy][tx] = src[(size_t)(y0 + yy) * C + x0 + tx];
    __syncthreads();
    for (int i = ty; i < 32; i += 8) {
        float v = t[tx][i];                        // src[y0+tx][x0+i]
        u16 h, l; split2(v, h, l);
        size_t o = (size_t)(x0 + i) * 1024 + y0 + tx;  // dst rows = src cols; R=1024
        dhi[o] = h; dlo[o] = l;
    }
}

// ---- stage 1: GEMM x @ [Wq|Wkv] + co-scheduled bias transpose.
// Block order: gemm blocks FIRST (0..767) so they get full co-residency;
// bias blocks (768..2815) backfill free slots and ride idle HBM BW.
// Q cols (bx<8): 3-term compensated. K/V cols: 1-term pure bf16 (they are
// bf16-rounded on store anyway; dropped-term error < rounding quantum).
// LDS swizzle: slot s of row r holds global K-group s^(r&3).
__global__ __launch_bounds__(256) void gemm_qkv_bias(
    int mode,
    const u16* __restrict__ Ah, const u16* __restrict__ Al,
    const u16* __restrict__ Bh, const u16* __restrict__ Bl,
    u16* __restrict__ qh, u16* __restrict__ ql,
    u16* __restrict__ kb, u16* __restrict__ vT,
    const float* __restrict__ bias, const int* __restrict__ mask,
    u16* __restrict__ biasT)
{
    __shared__ __align__(16) char smem[32768];
    const int tid = threadIdx.x;

    int gid = -1, bid = -1;
    if (mode == 1) {
        if (blockIdx.x < 768) gid = blockIdx.x; else bid = blockIdx.x - 768;
    } else if (mode == 0) gid = blockIdx.x;
    else bid = blockIdx.x;

    if (bid >= 0) {
        // ---- bias path: biasT[b][k][q] = mask ? bf16(bias[b][q][k]) : -1e30 ----
        float (*t)[65] = (float(*)[65])smem;
        const int b = bid >> 10, rest = bid & 1023;
        const int k0 = (rest & 31) * 64, q0 = (rest >> 5) * 64;
#pragma unroll
        for (int it = 0; it < 16; it++) {
            int idx = it * 256 + tid;
            int qq = idx >> 6, kk = idx & 63;
            t[qq][kk] = bias[((size_t)b * N_ + q0 + qq) * N_ + k0 + kk];
        }
        __syncthreads();
        const u16 NEG = f2bf(-1e30f);
#pragma unroll
        for (int it = 0; it < 16; it++) {
            int idx = it * 256 + tid;
            int kk = idx >> 6, qq = idx & 63;
            int mok = mask[b * N_ + k0 + kk];
            biasT[((size_t)b * N_ + k0 + kk) * N_ + q0 + qq] = mok ? f2bf(t[qq][kk]) : NEG;
        }
        return;
    }

    // ---- gemm path ----
    u16* sAh = (u16*)smem;
    u16* sAl = (u16*)(smem + 8192);
    u16* sBh = (u16*)(smem + 16384);
    u16* sBl = (u16*)(smem + 24576);
    const int wave = tid >> 6, lane = tid & 63;
    const int quad = lane >> 4, l16 = lane & 15;
    const int wm = wave >> 1, wn = wave & 1;
    const int bx = gid % 24, by = gid / 24;
    const int bm = by * 128, bn = bx * 128;
    const bool comp = (bx < 8);   // Q columns: 3-term compensation

    f32x4 acc[4][4];
#pragma unroll
    for (int i = 0; i < 4; i++)
#pragma unroll
        for (int j = 0; j < 4; j++) acc[i][j] = (f32x4){0.f, 0.f, 0.f, 0.f};

    const int row0 = tid >> 2, g4 = tid & 3;
    const int r1 = row0, r2 = row0 + 64;
    const int gc1 = (g4 ^ (r1 & 3)) * 8, gc2 = (g4 ^ (r2 & 3)) * 8;
    const size_t a1 = (size_t)(bm + r1) * 1024 + gc1, a2 = (size_t)(bm + r2) * 1024 + gc2;
    const size_t b1 = (size_t)(bn + r1) * 1024 + gc1, b2 = (size_t)(bn + r2) * 1024 + gc2;
    const int w1 = r1 * 32 + g4 * 8, w2 = r2 * 32 + g4 * 8;   // slot index = g4 (data group g4^(r&3))

    if (comp) {
        bf16x8 pAh0, pAh1, pAl0, pAl1, pBh0, pBh1, pBl0, pBl1;
        pAh0 = *(const bf16x8*)&Ah[a1]; pAh1 = *(const bf16x8*)&Ah[a2];
        pAl0 = *(const bf16x8*)&Al[a1]; pAl1 = *(const bf16x8*)&Al[a2];
        pBh0 = *(const bf16x8*)&Bh[b1]; pBh1 = *(const bf16x8*)&Bh[b2];
        pBl0 = *(const bf16x8*)&Bl[b1]; pBl1 = *(const bf16x8*)&Bl[b2];
        for (int k0 = 0; k0 < 1024; k0 += 32) {
            *(bf16x8*)&sAh[w1] = pAh0; *(bf16x8*)&sAh[w2] = pAh1;
            *(bf16x8*)&sAl[w1] = pAl0; *(bf16x8*)&sAl[w2] = pAl1;
            *(bf16x8*)&sBh[w1] = pBh0; *(bf16x8*)&sBh[w2] = pBh1;
            *(bf16x8*)&sBl[w1] = pBl0; *(bf16x8*)&sBl[w2] = pBl1;
            __syncthreads();
            if (k0 + 32 < 1024) {
                int kn = k0 + 32;
                pAh0 = *(const bf16x8*)&Ah[a1 + kn]; pAh1 = *(const bf16x8*)&Ah[a2 + kn];
                pAl0 = *(const bf16x8*)&Al[a1 + kn]; pAl1 = *(const bf16x8*)&Al[a2 + kn];
                pBh0 = *(const bf16x8*)&Bh[b1 + kn]; pBh1 = *(const bf16x8*)&Bh[b2 + kn];
                pBl0 = *(const bf16x8*)&Bl[b1 + kn]; pBl1 = *(const bf16x8*)&Bl[b2 + kn];
            }
            bf16x8 fah[4], fal[4], fbh[4], fbl[4];
#pragma unroll
            for (int s = 0; s < 4; s++) {
                int ra = wm * 64 + s * 16 + l16;
                int rb = wn * 64 + s * 16 + l16;
                int ca = (quad ^ (ra & 3)) * 8;
                int cb = (quad ^ (rb & 3)) * 8;
                fah[s] = *(const bf16x8*)&sAh[ra * 32 + ca];
                fal[s] = *(const bf16x8*)&sAl[ra * 32 + ca];
                fbh[s] = *(const bf16x8*)&sBh[rb * 32 + cb];
                fbl[s] = *(const bf16x8*)&sBl[rb * 32 + cb];
            }
#pragma unroll
            for (int sm = 0; sm < 4; sm++)
#pragma unroll
                for (int sn = 0; sn < 4; sn++) {
                    acc[sm][sn] = __builtin_amdgcn_mfma_f32_16x16x32_bf16(fah[sm], fbh[sn], acc[sm][sn], 0, 0, 0);
                    acc[sm][sn] = __builtin_amdgcn_mfma_f32_16x16x32_bf16(fal[sm], fbh[sn], acc[sm][sn], 0, 0, 0);
                    acc[sm][sn] = __builtin_amdgcn_mfma_f32_16x16x32_bf16(fah[sm], fbl[sn], acc[sm][sn], 0, 0, 0);
                }
            __syncthreads();
        }
    } else {
        // 1-term: K/V columns, pure bf16
        bf16x8 pAh0, pAh1, pBh0, pBh1;
        pAh0 = *(const bf16x8*)&Ah[a1]; pAh1 = *(const bf16x8*)&Ah[a2];
        pBh0 = *(const bf16x8*)&Bh[b1]; pBh1 = *(const bf16x8*)&Bh[b2];
        for (int k0 = 0; k0 < 1024; k0 += 32) {
            *(bf16x8*)&sAh[w1] = pAh0; *(bf16x8*)&sAh[w2] = pAh1;
            *(bf16x8*)&sBh[w1] = pBh0; *(bf16x8*)&sBh[w2] = pBh1;
            __syncthreads();
            if (k0 + 32 < 1024) {
                int kn = k0 + 32;
                pAh0 = *(const bf16x8*)&Ah[a1 + kn]; pAh1 = *(const bf16x8*)&Ah[a2 + kn];
                pBh0 = *(const bf16x8*)&Bh[b1 + kn]; pBh1 = *(const bf16x8*)&Bh[b2 + kn];
            }
            bf16x8 fah[4], fbh[4];
#pragma unroll
            for (int s = 0; s < 4; s++) {
                int ra = wm * 64 + s * 16 + l16;
                int rb = wn * 64 + s * 16 + l16;
                int ca = (quad ^ (ra & 3)) * 8;
                int cb = (quad ^ (rb & 3)) * 8;
                fah[s] = *(const bf16x8*)&sAh[ra * 32 + ca];
                fbh[s] = *(const bf16x8*)&sBh[rb * 32 + cb];
            }
#pragma unroll
            for (int sm = 0; sm < 4; sm++)
#pragma unroll
                for (int sn = 0; sn < 4; sn++)
                    acc[sm][sn] = __builtin_amdgcn_mfma_f32_16x16x32_bf16(fah[sm], fbh[sn], acc[sm][sn], 0, 0, 0);
            __syncthreads();
        }
    }
#pragma unroll
    for (int sm = 0; sm < 4; sm++) {
        int rowb = bm + wm * 64 + sm * 16 + quad * 4;
        int bb = rowb >> 11, i0 = rowb & 2047;
#pragma unroll
        for (int sn = 0; sn < 4; sn++) {
            int col = bn + wn * 64 + sn * 16 + l16;
            int region = col >> 10;
            int hh = (col >> 6) & 15;
            int d = col & 63;
            if (region == 0) {
#pragma unroll
                for (int r = 0; r < 4; r++) {
                    float val = acc[sm][sn][r] * SCALE_;
                    u16 a, c; split2(val, a, c);
                    size_t o = (((size_t)(bb * H_ + hh)) * N_ + i0 + r) * DH_ + d;
                    qh[o] = a; ql[o] = c;
                }
            } else if (region == 1) {
#pragma unroll
                for (int r = 0; r < 4; r++) {
                    size_t o = (((size_t)(bb * H_ + hh)) * N_ + i0 + r) * DH_ + d;
                    kb[o] = f2bf(acc[sm][sn][r]);
                }
            } else {
                u16x4 pv;
#pragma unroll
                for (int r = 0; r < 4; r++) pv[r] = f2bf(acc[sm][sn][r]);
                *(u16x4*)&vT[(((size_t)(bb * H_ + hh)) * DH_ + d) * N_ + i0] = pv;
            }
        }
    }
}

// ---- stage 3: O(bf16) @ Wo(hi/lo) + bo -> fp32. 128x64 tiles, 512 blocks
// (2/CU) for latency hiding; wave grid 2x2, per-wave 64x32 output.
__global__ __launch_bounds__(256) void gemm_out(
    const u16* __restrict__ Ab,
    const u16* __restrict__ Bh, const u16* __restrict__ Bl,
    const float* __restrict__ bo, float* __restrict__ out)
{
    __shared__ __align__(16) u16 sA[128 * 32], sBh[64 * 32], sBl[64 * 32];
    const int tid = threadIdx.x;
    const int wave = tid >> 6, lane = tid & 63;
    const int quad = lane >> 4, l16 = lane & 15;
    const int wm = wave >> 1, wn = wave & 1;
    const int bm = blockIdx.y * 128, bn = blockIdx.x * 64;

    f32x4 acc[4][2];
#pragma unroll
    for (int i = 0; i < 4; i++)
#pragma unroll
        for (int j = 0; j < 2; j++) acc[i][j] = (f32x4){0.f, 0.f, 0.f, 0.f};

    const int row0 = tid >> 2, g4 = tid & 3;
    const int r1 = row0, r2 = row0 + 64;     // A rows
    const int rb0 = tid >> 2;                 // B rows 0..63
    const int gc1 = (g4 ^ (r1 & 3)) * 8, gc2 = (g4 ^ (r2 & 3)) * 8;
    const size_t a1 = (size_t)(bm + r1) * 1024 + gc1, a2 = (size_t)(bm + r2) * 1024 + gc2;
    const size_t bgo = (size_t)(bn + rb0) * 1024 + gc1;
    const int w1 = r1 * 32 + g4 * 8, w2 = r2 * 32 + g4 * 8;
    const int wb = rb0 * 32 + g4 * 8;

    bf16x8 pA0, pA1, pBh0, pBl0;
    pA0 = *(const bf16x8*)&Ab[a1]; pA1 = *(const bf16x8*)&Ab[a2];
    pBh0 = *(const bf16x8*)&Bh[bgo]; pBl0 = *(const bf16x8*)&Bl[bgo];

    for (int k0 = 0; k0 < 1024; k0 += 32) {
        *(bf16x8*)&sA[w1] = pA0;  *(bf16x8*)&sA[w2] = pA1;
        *(bf16x8*)&sBh[wb] = pBh0; *(bf16x8*)&sBl[wb] = pBl0;
        __syncthreads();
        if (k0 + 32 < 1024) {
            int kn = k0 + 32;
            pA0 = *(const bf16x8*)&Ab[a1 + kn]; pA1 = *(const bf16x8*)&Ab[a2 + kn];
            pBh0 = *(const bf16x8*)&Bh[bgo + kn]; pBl0 = *(const bf16x8*)&Bl[bgo + kn];
        }
        bf16x8 fa[4], fbh[2], fbl[2];
#pragma unroll
        for (int s = 0; s < 4; s++) {
            int ra = wm * 64 + s * 16 + l16;
            int ca = (quad ^ (ra & 3)) * 8;
            fa[s] = *(const bf16x8*)&sA[ra * 32 + ca];
        }
#pragma unroll
        for (int s = 0; s < 2; s++) {
            int rb = wn * 32 + s * 16 + l16;
            int cb = (quad ^ (rb & 3)) * 8;
            fbh[s] = *(const bf16x8*)&sBh[rb * 32 + cb];
            fbl[s] = *(const bf16x8*)&sBl[rb * 32 + cb];
        }
#pragma unroll
        for (int sm = 0; sm < 4; sm++)
#pragma unroll
            for (int sn = 0; sn < 2; sn++) {
                acc[sm][sn] = __builtin_amdgcn_mfma_f32_16x16x32_bf16(fa[sm], fbh[sn], acc[sm][sn], 0, 0, 0);
                acc[sm][sn] = __builtin_amdgcn_mfma_f32_16x16x32_bf16(fa[sm], fbl[sn], acc[sm][sn], 0, 0, 0);
            }
        __syncthreads();
    }
#pragma unroll
    for (int sm = 0; sm < 4; sm++) {
        int rowb = bm + wm * 64 + sm * 16 + quad * 4;
#pragma unroll
        for (int sn = 0; sn < 2; sn++) {
            int col = bn + wn * 32 + sn * 16 + l16;
            float bv = bo[col];
#pragma unroll
            for (int r = 0; r < 4; r++)
                out[(size_t)(rowb + r) * 1024 + col] = acc[sm][sn][r] + bv;
        }
    }
}

// ---- stage 2: flash attention; keys partitioned across waves ----
#define LDK 72    // sK  [128 keys][64 d]   stride
#define LDV 136   // sVt [64 d][128 keys]   stride
#define LDB 72    // sBt [128 keys][64 q]   stride
#define LDP 40    // sP  [4][64 q][32 keys] stride

__global__ __launch_bounds__(256, 2) void attn_kernel(
    const u16* __restrict__ qh, const u16* __restrict__ ql,
    const u16* __restrict__ kb, const u16* __restrict__ vT,
    const u16* __restrict__ biasT, u16* __restrict__ ob)
{
    __shared__ __align__(16) char smem[74752];
    u16* sK  = (u16*)smem;               // 128*72*2  = 18432
    u16* sVt = (u16*)(smem + 18432);     // 64*136*2  = 17408
    u16* sBt = (u16*)(smem + 35840);     // 128*72*2  = 18432
    u16* sP  = (u16*)(smem + 54272);     // 4*64*40*2 = 20480
    float* rO = (float*)smem;            // epilogue alias [4][64][68] f32
    float* rL = (float*)(smem + 69632);  // [4][64] f32

    const int bh = blockIdx.x, b = bh >> 4, h = bh & 15;
    const int qbase = blockIdx.y * 64;
    const int tid = threadIdx.x, wave = tid >> 6, lane = tid & 63;
    const int quad = lane >> 4, l16 = lane & 15;

    bf16x8 aqh_[4][2], aql_[4][2];
#pragma unroll
    for (int m = 0; m < 4; m++) {
        size_t qo = ((size_t)bh * N_ + qbase + m * 16 + l16) * DH_ + quad * 8;
#pragma unroll
        for (int s = 0; s < 2; s++) {
            aqh_[m][s] = *(const bf16x8*)&qh[qo + s * 32];
            aql_[m][s] = *(const bf16x8*)&ql[qo + s * 32];
        }
    }
    f32x4 Oacc[4][4], lacc[4];
#pragma unroll
    for (int m = 0; m < 4; m++) {
        lacc[m] = (f32x4){0.f, 0.f, 0.f, 0.f};
#pragma unroll
        for (int nd = 0; nd < 4; nd++) Oacc[m][nd] = (f32x4){0.f, 0.f, 0.f, 0.f};
    }
    bf16x8 ones;
#pragma unroll
    for (int i = 0; i < 8; i++) ones[i] = (short)0x3F80;

    const int rK = tid >> 3, cK = (tid & 7) * 8;
    const int rV = tid >> 4, cV = (tid & 15) * 8;
    const size_t kgbase = (size_t)bh * N_ * DH_;
    const size_t vgbase = (size_t)bh * DH_ * N_;
    const size_t bgbase = (size_t)b * N_ * N_ + qbase;

    bf16x8 pK[4], pV[4], pB[4];
#pragma unroll
    for (int it = 0; it < 4; it++) {
        pK[it] = *(const bf16x8*)&kb[kgbase + (size_t)(rK + it * 32) * DH_ + cK];
        pV[it] = *(const bf16x8*)&vT[vgbase + (size_t)(rV + it * 16) * N_ + cV];
        pB[it] = *(const bf16x8*)&biasT[bgbase + (size_t)(rK + it * 32) * N_ + cK];
    }

    for (int jt = 0; jt < 16; jt++) {
#pragma unroll
        for (int it = 0; it < 4; it++) {
            *(bf16x8*)&sK[(rK + it * 32) * LDK + cK] = pK[it];
            *(bf16x8*)&sVt[(rV + it * 16) * LDV + cV] = pV[it];
            *(bf16x8*)&sBt[(rK + it * 32) * LDB + cK] = pB[it];
        }
        __syncthreads();
        {
            int j0n = ((jt + 1) & 15) * 128;
#pragma unroll
            for (int it = 0; it < 4; it++) {
                pK[it] = *(const bf16x8*)&kb[kgbase + (size_t)(j0n + rK + it * 32) * DH_ + cK];
                pV[it] = *(const bf16x8*)&vT[vgbase + (size_t)(rV + it * 16) * N_ + j0n + cV];
                pB[it] = *(const bf16x8*)&biasT[bgbase + (size_t)(j0n + rK + it * 32) * N_ + cK];
            }
        }
        bf16x8 kf[2][2], vf[4];
#pragma unroll
        for (int n = 0; n < 2; n++)
#pragma unroll
            for (int s = 0; s < 2; s++)
                kf[n][s] = *(const bf16x8*)&sK[(wave * 32 + n * 16 + l16) * LDK + s * 32 + quad * 8];
#pragma unroll
        for (int nd = 0; nd < 4; nd++)
            vf[nd] = *(const bf16x8*)&sVt[(nd * 16 + l16) * LDV + wave * 32 + quad * 8];

#pragma unroll
        for (int m = 0; m < 4; m++) {
            f32x4 S0 = (f32x4){0.f, 0.f, 0.f, 0.f};
            f32x4 S1 = (f32x4){0.f, 0.f, 0.f, 0.f};
#pragma unroll
            for (int s = 0; s < 2; s++) {
                S0 = __builtin_amdgcn_mfma_f32_16x16x32_bf16(aqh_[m][s], kf[0][s], S0, 0, 0, 0);
                S0 = __builtin_amdgcn_mfma_f32_16x16x32_bf16(aql_[m][s], kf[0][s], S0, 0, 0, 0);
                S1 = __builtin_amdgcn_mfma_f32_16x16x32_bf16(aqh_[m][s], kf[1][s], S1, 0, 0, 0);
                S1 = __builtin_amdgcn_mfma_f32_16x16x32_bf16(aql_[m][s], kf[1][s], S1, 0, 0, 0);
            }
            u16x4 b0 = *(const u16x4*)&sBt[(wave * 32 + l16) * LDB + m * 16 + quad * 4];
            u16x4 b1 = *(const u16x4*)&sBt[(wave * 32 + 16 + l16) * LDB + m * 16 + quad * 4];
#pragma unroll
            for (int r = 0; r < 4; r++) {
                S0[r] = __expf(S0[r] + bf2f(b0[r]));
                S1[r] = __expf(S1[r] + bf2f(b1[r]));
            }
            u16* pw = sP + (wave * 64 + m * 16 + quad * 4) * LDP;
#pragma unroll
            for (int r = 0; r < 4; r++) {
                pw[r * LDP + l16] = f2bf(S0[r]);
                pw[r * LDP + 16 + l16] = f2bf(S1[r]);
            }
            bf16x8 pa = *(const bf16x8*)&sP[(wave * 64 + m * 16 + l16) * LDP + quad * 8];
            lacc[m] = __builtin_amdgcn_mfma_f32_16x16x32_bf16(pa, ones, lacc[m], 0, 0, 0);
#pragma unroll
            for (int nd = 0; nd < 4; nd++)
                Oacc[m][nd] = __builtin_amdgcn_mfma_f32_16x16x32_bf16(pa, vf[nd], Oacc[m][nd], 0, 0, 0);
        }
        __syncthreads();
    }

#pragma unroll
    for (int m = 0; m < 4; m++)
#pragma unroll
        for (int nd = 0; nd < 4; nd++)
#pragma unroll
            for (int r = 0; r < 4; r++)
                rO[(wave * 64 + m * 16 + quad * 4 + r) * 68 + nd * 16 + l16] = Oacc[m][nd][r];
    if (l16 == 0) {
#pragma unroll
        for (int m = 0; m < 4; m++)
#pragma unroll
            for (int r = 0; r < 4; r++)
                rL[wave * 64 + m * 16 + quad * 4 + r] = lacc[m][r];
    }
    __syncthreads();
    {
        const int q = tid >> 2, dg = (tid & 3) * 16;
        float l = rL[q] + rL[64 + q] + rL[128 + q] + rL[192 + q];
        float inv = 1.f / l;
        f32x4 s[4];
#pragma unroll
        for (int i4 = 0; i4 < 4; i4++) s[i4] = *(const f32x4*)&rO[(size_t)q * 68 + dg + i4 * 4];
#pragma unroll
        for (int w = 1; w < 4; w++)
#pragma unroll
            for (int i4 = 0; i4 < 4; i4++) {
                f32x4 v = *(const f32x4*)&rO[(size_t)(w * 64 + q) * 68 + dg + i4 * 4];
                s[i4] += v;
            }
        size_t obase = ((size_t)b * N_ + qbase + q) * INNER_ + h * 64 + dg;
#pragma unroll
        for (int i4 = 0; i4 < 4; i4++) {
            u16x4 o4;
#pragma unroll
            for (int r = 0; r < 4; r++) o4[r] = f2bf(s[i4][r] * inv);
            *(u16x4*)&ob[obase + i4 * 4] = o4;
        }
    }
}

extern "C" void kernel_launch(void* const* d_in, const int* in_sizes, int n_in,
                              void* d_out, int out_size, void* d_ws, size_t ws_size,
                              hipStream_t stream)
{
    const float* x    = (const float*)d_in[0];
    const float* bias = (const float*)d_in[1];
    const int*   mask = (const int*)d_in[2];
    const float* Wq   = (const float*)d_in[3];
    const float* Wkv  = (const float*)d_in[4];
    const float* Wo   = (const float*)d_in[5];
    const float* bo   = (const float*)d_in[6];
    float* out = (float*)d_out;

    char* w = (char*)d_ws;
    const size_t MB = 1024 * 1024;
    u16* q_h   = (u16*)(w);             //  0..8   [32][2048][64]
    u16* q_l   = (u16*)(w + 8 * MB);
    u16* k_b   = (u16*)(w + 16 * MB);
    u16* v_T   = (u16*)(w + 24 * MB);   // [32][64][2048]
    u16* xs_h  = (u16*)(w + 32 * MB);
    u16* xs_l  = (u16*)(w + 40 * MB);
    u16* wT_h  = (u16*)(w + 48 * MB);   // [3072][1024]
    u16* wT_l  = (u16*)(w + 54 * MB);
    u16* woT_h = (u16*)(w + 60 * MB);
    u16* woT_l = (u16*)(w + 62 * MB);
    u16* o_b   = (u16*)(w + 64 * MB);   // [2][2048][1024]

    const size_t biasT_bytes = (size_t)2 * N_ * N_ * sizeof(u16);   // 16.78 MB
    const bool concurrent = ws_size >= 72 * MB + biasT_bytes;

    prep_kernel<<<8192, 256, 0, stream>>>(x, xs_h, xs_l, Wq, Wkv, Wo, wT_h, wT_l, woT_h, woT_l);

    if (concurrent) {
        u16* biasT = (u16*)(w + 72 * MB);   // disjoint: safe alongside gemm reads
        gemm_qkv_bias<<<2816, 256, 0, stream>>>(1, xs_h, xs_l, wT_h, wT_l,
                                                q_h, q_l, k_b, v_T, bias, mask, biasT);
        attn_kernel<<<dim3(32, 32), 256, 0, stream>>>(q_h, q_l, k_b, v_T, biasT, o_b);
    } else {
        u16* biasT = (u16*)(w + 32 * MB);   // aliases xs (dead after gemm) — sequential only
        gemm_qkv_bias<<<768, 256, 0, stream>>>(0, xs_h, xs_l, wT_h, wT_l,
                                               q_h, q_l, k_b, v_T, bias, mask, biasT);
        gemm_qkv_bias<<<2048, 256, 0, stream>>>(2, xs_h, xs_l, wT_h, wT_l,
                                                q_h, q_l, k_b, v_T, bias, mask, biasT);
        attn_kernel<<<dim3(32, 32), 256, 0, stream>>>(q_h, q_l, k_b, v_T, biasT, o_b);
    }
    gemm_out<<<dim3(16, 32), 256, 0, stream>>>(o_b, woT_h, woT_l, bo, out);
}